// Round 1
// baseline (42710.410 us; speedup 1.0000x reference)
//
#include <hip/hip_runtime.h>
#include <math.h>

#define B_DIM   8192
#define N_DIM   784
#define M_DIM   2048
#define XSZ     (B_DIM*N_DIM)      // 6422528
#define GSZ     (B_DIM*M_DIM)      // 16777216
#define NITER   50
#define PITER   100

#define TILE 128
#define BK   16
#define LDSS 132   // 128 + 4 pad

// ---------------- threefry + erfinv (reproduce jax.random.normal(key(1),(1,2048))) ------------
__device__ __forceinline__ unsigned rotl32(unsigned x, int d){ return (x<<d)|(x>>(32-d)); }

__device__ void threefry2x32(unsigned& v0, unsigned& v1){
  const unsigned ks0=0u, ks1=1u, ks2=0x1BD11BDBu; // 0^1^0x1BD11BDA
  unsigned x0=v0+ks0, x1=v1+ks1;
#define RND(R) { x0+=x1; x1=rotl32(x1,R); x1^=x0; }
  RND(13) RND(15) RND(26) RND(6)
  x0+=ks1; x1+=ks2+1u;
  RND(17) RND(29) RND(16) RND(24)
  x0+=ks2; x1+=ks0+2u;
  RND(13) RND(15) RND(26) RND(6)
  x0+=ks0; x1+=ks1+3u;
  RND(17) RND(29) RND(16) RND(24)
  x0+=ks1; x1+=ks2+4u;
  RND(13) RND(15) RND(26) RND(6)
  x0+=ks2; x1+=ks0+5u;
#undef RND
  v0=x0; v1=x1;
}

__device__ float erfinv_f(float x){
  float w = -logf((1.0f-x)*(1.0f+x));
  float p;
  if (w < 5.0f){
    w -= 2.5f;
    p = 2.81022636e-08f;
    p = fmaf(p,w, 3.43273939e-07f);
    p = fmaf(p,w,-3.5233877e-06f);
    p = fmaf(p,w,-4.39150654e-06f);
    p = fmaf(p,w, 0.00021858087f);
    p = fmaf(p,w,-0.00125372503f);
    p = fmaf(p,w,-0.00417768164f);
    p = fmaf(p,w, 0.246640727f);
    p = fmaf(p,w, 1.50140941f);
  } else {
    w = sqrtf(w) - 3.0f;
    p = -0.000200214257f;
    p = fmaf(p,w, 0.000100950558f);
    p = fmaf(p,w, 0.00134934322f);
    p = fmaf(p,w,-0.00367342844f);
    p = fmaf(p,w, 0.00573950773f);
    p = fmaf(p,w,-0.0076224613f);
    p = fmaf(p,w, 0.00943887047f);
    p = fmaf(p,w, 1.00167406f);
    p = fmaf(p,w, 2.83297682f);
  }
  return p*x;
}

__device__ float bits_to_normal(unsigned b){
  unsigned fb = (b>>9) | 0x3f800000u;
  float u01 = __uint_as_float(fb) - 1.0f;          // [0,1)
  const float lo = -0.99999994f;                   // nextafter(-1,0)
  float u = u01*(1.0f - lo) + lo;
  u = fmaxf(lo, u);
  return 1.41421356237f * erfinv_f(u);
}

// setup: X0 via threefry, zero accumulators (accs[0]=||Y||^2 acc, accs[1..50]=per-iter ||R||^2)
__global__ void setup_kernel(float* __restrict__ xbuf0, float* __restrict__ accs){
  int i = threadIdx.x;   // 1024 threads
  if (i < 64) accs[i] = 0.0f;
  unsigned v0 = (unsigned)i, v1 = (unsigned)(1024+i);
  threefry2x32(v0, v1);
  xbuf0[i]        = bits_to_normal(v0);
  xbuf0[1024 + i] = bits_to_normal(v1);
}

// ---------------- reductions ----------------
__global__ void sumsq_kernel(const float* __restrict__ v, int n, float* __restrict__ acc){
  __shared__ float red[256];
  int t = threadIdx.x;
  float s = 0.0f;
  for (int i = blockIdx.x*256 + t; i < n; i += gridDim.x*256){ float x = v[i]; s = fmaf(x,x,s); }
  red[t] = s; __syncthreads();
  for (int off=128; off>0; off>>=1){ if (t<off) red[t]+=red[t+off]; __syncthreads(); }
  if (t==0) atomicAdd(acc, red[0]);
}

// ---------------- power method ----------------
// t[j] = (x_hat . W[j,:]) ; x_hat = x/||x||   (196 blocks x 4 waves = 784 rows)
__global__ void pm_xwT(const float* __restrict__ x, const float* __restrict__ Wm,
                       float* __restrict__ tout){
  __shared__ float red[256];
  int t = threadIdx.x;
  float s = 0.0f;
  for (int k=t; k<M_DIM; k+=256){ float v = x[k]; s = fmaf(v,v,s); }
  red[t]=s; __syncthreads();
  for (int off=128; off>0; off>>=1){ if (t<off) red[t]+=red[t+off]; __syncthreads(); }
  float inv = 1.0f/sqrtf(red[0]);
  int wave = t>>6, lane = t&63;
  int j = blockIdx.x*4 + wave;
  const float* Wr = Wm + (size_t)j*M_DIM;
  float acc = 0.0f;
  for (int k=lane; k<M_DIM; k+=64) acc = fmaf(x[k], Wr[k], acc);
  for (int off=32; off>0; off>>=1) acc += __shfl_down(acc, off);
  if (lane==0) tout[j] = acc * inv;
}

// x_next[k] = sum_j t[j]*W[j,k]   (8 blocks x 256 = 2048 outputs)
__global__ void pm_tw(const float* __restrict__ tin, const float* __restrict__ Wm,
                      float* __restrict__ xout){
  int k = blockIdx.x*256 + threadIdx.x;
  float a0=0.f,a1=0.f,a2=0.f,a3=0.f;
  for (int j=0; j<N_DIM; j+=4){
    a0 = fmaf(tin[j+0], Wm[(size_t)(j+0)*M_DIM + k], a0);
    a1 = fmaf(tin[j+1], Wm[(size_t)(j+1)*M_DIM + k], a1);
    a2 = fmaf(tin[j+2], Wm[(size_t)(j+2)*M_DIM + k], a2);
    a3 = fmaf(tin[j+3], Wm[(size_t)(j+3)*M_DIM + k], a3);
  }
  xout[k] = (a0+a1)+(a2+a3);
}

// params: [0]=c, [1]=eta=1/c, [2]=lam/c, [3]=||Y||
__global__ void finish_power(const float* __restrict__ xfin, const float* __restrict__ accs,
                             float* __restrict__ params){
  __shared__ float red[256];
  int t = threadIdx.x;
  float s = 0.0f;
  for (int k=t; k<M_DIM; k+=256){ float v = xfin[k]; s = fmaf(v,v,s); }
  red[t]=s; __syncthreads();
  for (int off=128; off>0; off>>=1){ if (t<off) red[t]+=red[t+off]; __syncthreads(); }
  if (t==0){
    float c = sqrtf(red[0]);
    params[0] = c;
    params[1] = 1.0f/c;
    params[2] = 0.1f/c;
    params[3] = sqrtf(accs[0]);
  }
}

__device__ __forceinline__ float softthr(float v, float th){
  float a = fmaxf(fabsf(v) - th, 0.0f);
  return copysignf(a, v);
}

// ---------------- GEMM NT: C[i,j] = sum_k A[i,k]*W[j,k]; i<8192 (grid.x=64), j<784 (grid.y=7), K=2048 ----
// MODE 0: R = A*W^T - Y, accumulate ||R||^2 into nacc.   MODE 1: Cout = A*W^T (final X).
template<int MODE>
__global__ __launch_bounds__(256)
void gemm_nt(const float* __restrict__ A, const float* __restrict__ Wm,
             const float* __restrict__ Y, float* __restrict__ Cout,
             float* __restrict__ nacc){
  __shared__ float As[BK][LDSS];
  __shared__ float Bs[BK][LDSS];
  __shared__ float red[256];
  const int t  = threadIdx.x;
  const int m0 = blockIdx.x*TILE, n0 = blockIdx.y*TILE;
  const int ty = t>>4, tx = t&15;
  float acc[8][8];
#pragma unroll
  for (int i=0;i<8;i++)
#pragma unroll
    for (int j=0;j<8;j++) acc[i][j]=0.0f;

  const int lrow = t>>2;
  const int lkq  = (t&3)*4;

  for (int k0=0; k0<M_DIM; k0+=BK){
#pragma unroll
    for (int h=0; h<2; ++h){
      int row = lrow + h*64;
      float4 v = *(const float4*)(A + (size_t)(m0+row)*M_DIM + k0 + lkq);
      As[lkq+0][row]=v.x; As[lkq+1][row]=v.y; As[lkq+2][row]=v.z; As[lkq+3][row]=v.w;
    }
#pragma unroll
    for (int h=0; h<2; ++h){
      int row = lrow + h*64;
      int j = n0 + row;
      float4 v = make_float4(0.f,0.f,0.f,0.f);
      if (j < N_DIM) v = *(const float4*)(Wm + (size_t)j*M_DIM + k0 + lkq);
      Bs[lkq+0][row]=v.x; Bs[lkq+1][row]=v.y; Bs[lkq+2][row]=v.z; Bs[lkq+3][row]=v.w;
    }
    __syncthreads();
#pragma unroll
    for (int kk=0; kk<BK; ++kk){
      float a[8], b[8];
      *(float4*)&a[0] = *(const float4*)&As[kk][ty*8];
      *(float4*)&a[4] = *(const float4*)&As[kk][ty*8+4];
      *(float4*)&b[0] = *(const float4*)&Bs[kk][tx*8];
      *(float4*)&b[4] = *(const float4*)&Bs[kk][tx*8+4];
#pragma unroll
      for (int i=0;i<8;i++)
#pragma unroll
        for (int j=0;j<8;j++) acc[i][j] = fmaf(a[i], b[j], acc[i][j]);
    }
    __syncthreads();
  }

  if (MODE==0){
    float ss = 0.0f;
#pragma unroll
    for (int i=0;i<8;i++){
      int gi = m0 + ty*8 + i;
#pragma unroll
      for (int j=0;j<8;j++){
        int gj = n0 + tx*8 + j;
        if (gj < N_DIM){
          size_t idx = (size_t)gi*N_DIM + gj;
          float r = acc[i][j] - Y[idx];
          Cout[idx] = r;
          ss = fmaf(r,r,ss);
        }
      }
    }
    red[t]=ss; __syncthreads();
    for (int off=128; off>0; off>>=1){ if (t<off) red[t]+=red[t+off]; __syncthreads(); }
    if (t==0) atomicAdd(nacc, red[0]);
  } else {
#pragma unroll
    for (int i=0;i<8;i++){
      int gi = m0 + ty*8 + i;
#pragma unroll
      for (int j=0;j<8;j++){
        int gj = n0 + tx*8 + j;
        if (gj < N_DIM) Cout[(size_t)gi*N_DIM + gj] = acc[i][j];
      }
    }
  }
}

// ---------------- GEMM NN: G[i,k] = sum_j A[i,j]*W[j,k]; A [8192x784], W [784x2048] ----
// MODE 0 (init, A=Y): g=soft(eta*G, 0.1); Gamma=Z=g.
// MODE 1 (iter, A=R): g=soft(Z - eta*G, lam/c); z=g+mu*(g-Gamma); Gamma=g; Z=z.
template<int MODE>
__global__ __launch_bounds__(256)
void gemm_nn(const float* __restrict__ A, const float* __restrict__ Wm,
             float* __restrict__ Gamma, float* __restrict__ Z,
             const float* __restrict__ params, float mu){
  __shared__ float As[BK][LDSS];
  __shared__ float Bs[BK][LDSS];
  const int t  = threadIdx.x;
  const int m0 = blockIdx.x*TILE, n0 = blockIdx.y*TILE;
  const int ty = t>>4, tx = t&15;
  float acc[8][8];
#pragma unroll
  for (int i=0;i<8;i++)
#pragma unroll
    for (int j=0;j<8;j++) acc[i][j]=0.0f;

  const int lrow = t>>2;
  const int lkq  = (t&3)*4;

  for (int k0=0; k0<N_DIM; k0+=BK){
#pragma unroll
    for (int h=0; h<2; ++h){
      int row = lrow + h*64;
      float4 v = *(const float4*)(A + (size_t)(m0+row)*N_DIM + k0 + lkq);
      As[lkq+0][row]=v.x; As[lkq+1][row]=v.y; As[lkq+2][row]=v.z; As[lkq+3][row]=v.w;
    }
#pragma unroll
    for (int h=0; h<2; ++h){
      int slot = h*256 + t;
      int kr = slot>>5, nq = slot&31;
      float4 v = *(const float4*)(Wm + (size_t)(k0+kr)*M_DIM + n0 + nq*4);
      *(float4*)&Bs[kr][nq*4] = v;
    }
    __syncthreads();
#pragma unroll
    for (int kk=0; kk<BK; ++kk){
      float a[8], b[8];
      *(float4*)&a[0] = *(const float4*)&As[kk][ty*8];
      *(float4*)&a[4] = *(const float4*)&As[kk][ty*8+4];
      *(float4*)&b[0] = *(const float4*)&Bs[kk][tx*8];
      *(float4*)&b[4] = *(const float4*)&Bs[kk][tx*8+4];
#pragma unroll
      for (int i=0;i<8;i++)
#pragma unroll
        for (int j=0;j<8;j++) acc[i][j] = fmaf(a[i], b[j], acc[i][j]);
    }
    __syncthreads();
  }

  float eta  = params[1];
  float lamc = params[2];
#pragma unroll
  for (int i=0;i<8;i++){
    int gi = m0 + ty*8 + i;
#pragma unroll
    for (int j=0;j<8;j++){
      int gj = n0 + tx*8 + j;
      size_t idx = (size_t)gi*M_DIM + gj;
      if (MODE==0){
        float g = softthr(eta*acc[i][j], 0.1f);
        Gamma[idx] = g;
        Z[idx]     = g;
      } else {
        float zv = Z[idx];
        float g  = softthr(zv - eta*acc[i][j], lamc);
        float go = Gamma[idx];
        float zn = g + mu*(g - go);
        Gamma[idx] = g;
        Z[idx]     = zn;
      }
    }
  }
}

__global__ void norms_finalize(const float* __restrict__ nacc, const float* __restrict__ params,
                               float* __restrict__ out){
  int i = threadIdx.x;
  if (i < NITER) out[i] = sqrtf(nacc[i]) / params[3];
}

extern "C" void kernel_launch(void* const* d_in, const int* in_sizes, int n_in,
                              void* d_out, int out_size, void* d_ws, size_t ws_size,
                              hipStream_t stream){
  const float* Y  = (const float*)d_in[0];
  const float* W  = (const float*)d_in[1];
  float* out      = (float*)d_out;
  float* X        = out;                 // [8192x784]
  float* Gamma    = out + XSZ;           // [8192x2048]
  float* norms    = out + XSZ + GSZ;     // [50]
  float* ws       = (float*)d_ws;
  float* Z        = ws;                  // [8192x2048]
  float* xb0      = ws + GSZ;
  float* xb1      = xb0 + M_DIM;
  float* tb       = xb1 + M_DIM;
  float* params   = tb + N_DIM;
  float* accs     = params + 8;          // accs[0]=||Y||^2, accs[1..50]=per-iter ||R||^2
  float* R        = X;                   // residual reuses X region until the end

  setup_kernel<<<dim3(1), dim3(1024), 0, stream>>>(xb0, accs);
  sumsq_kernel<<<dim3(512), dim3(256), 0, stream>>>(Y, XSZ, accs);

  float* xa = xb0; float* xc = xb1;
  for (int it=0; it<PITER; ++it){
    pm_xwT<<<dim3(196), dim3(256), 0, stream>>>(xa, W, tb);
    pm_tw <<<dim3(8),   dim3(256), 0, stream>>>(tb, W, xc);
    float* tmp = xa; xa = xc; xc = tmp;
  }
  finish_power<<<dim3(1), dim3(256), 0, stream>>>(xa, accs, params);

  // Gamma0 = soft(eta * (Y@W), lam); Z0 = Gamma0
  gemm_nn<0><<<dim3(64,16), dim3(256), 0, stream>>>(Y, W, Gamma, Z, params, 0.0f);

  float tcur = 1.0f;
  for (int it=0; it<NITER; ++it){
    gemm_nt<0><<<dim3(64,7), dim3(256), 0, stream>>>(Z, W, Y, R, accs + 1 + it);
    float tsq = tcur*tcur;
    float tn  = (1.0f + sqrtf(1.0f + 4.0f*tsq)) / 2.0f;
    float mu  = (tcur - 1.0f) / tn;
    tcur = tn;
    gemm_nn<1><<<dim3(64,16), dim3(256), 0, stream>>>(R, W, Gamma, Z, params, mu);
  }

  // X = Gamma @ W^T
  gemm_nt<1><<<dim3(64,7), dim3(256), 0, stream>>>(Gamma, W, Y, X, nullptr);
  norms_finalize<<<dim3(1), dim3(64), 0, stream>>>(accs + 1, params, norms);
}

// Round 2
// 13112.100 us; speedup vs baseline: 3.2573x; 3.2573x over previous
//
#include <hip/hip_runtime.h>
#include <math.h>

#define B_DIM   8192
#define N_DIM   784
#define NPAD    800          // 25*32, K-pad for the NN GEMM
#define M_DIM   2048
#define XSZ     (B_DIM*N_DIM)
#define GSZ     (B_DIM*M_DIM)
#define NITER   50
#define PITER   100

typedef __attribute__((ext_vector_type(8))) short short8;
typedef __attribute__((ext_vector_type(4))) float floatx4;

// ---------------- threefry + erfinv (reproduce jax.random.normal(key(1),(1,2048))) ------------
__device__ __forceinline__ unsigned rotl32(unsigned x, int d){ return (x<<d)|(x>>(32-d)); }

__device__ void threefry2x32(unsigned& v0, unsigned& v1){
  const unsigned ks0=0u, ks1=1u, ks2=0x1BD11BDBu;
  unsigned x0=v0+ks0, x1=v1+ks1;
#define RND(R) { x0+=x1; x1=rotl32(x1,R); x1^=x0; }
  RND(13) RND(15) RND(26) RND(6)
  x0+=ks1; x1+=ks2+1u;
  RND(17) RND(29) RND(16) RND(24)
  x0+=ks2; x1+=ks0+2u;
  RND(13) RND(15) RND(26) RND(6)
  x0+=ks0; x1+=ks1+3u;
  RND(17) RND(29) RND(16) RND(24)
  x0+=ks1; x1+=ks2+4u;
  RND(13) RND(15) RND(26) RND(6)
  x0+=ks2; x1+=ks0+5u;
#undef RND
  v0=x0; v1=x1;
}

__device__ float erfinv_f(float x){
  float w = -logf((1.0f-x)*(1.0f+x));
  float p;
  if (w < 5.0f){
    w -= 2.5f;
    p = 2.81022636e-08f;
    p = fmaf(p,w, 3.43273939e-07f);
    p = fmaf(p,w,-3.5233877e-06f);
    p = fmaf(p,w,-4.39150654e-06f);
    p = fmaf(p,w, 0.00021858087f);
    p = fmaf(p,w,-0.00125372503f);
    p = fmaf(p,w,-0.00417768164f);
    p = fmaf(p,w, 0.246640727f);
    p = fmaf(p,w, 1.50140941f);
  } else {
    w = sqrtf(w) - 3.0f;
    p = -0.000200214257f;
    p = fmaf(p,w, 0.000100950558f);
    p = fmaf(p,w, 0.00134934322f);
    p = fmaf(p,w,-0.00367342844f);
    p = fmaf(p,w, 0.00573950773f);
    p = fmaf(p,w,-0.0076224613f);
    p = fmaf(p,w, 0.00943887047f);
    p = fmaf(p,w, 1.00167406f);
    p = fmaf(p,w, 2.83297682f);
  }
  return p*x;
}

__device__ float bits_to_normal(unsigned b){
  unsigned fb = (b>>9) | 0x3f800000u;
  float u01 = __uint_as_float(fb) - 1.0f;
  const float lo = -0.99999994f;
  float u = u01*(1.0f - lo) + lo;
  u = fmaxf(lo, u);
  return 1.41421356237f * erfinv_f(u);
}

__global__ void setup_kernel(float* __restrict__ xbuf0, float* __restrict__ accs){
  int i = threadIdx.x;   // 1024 threads
  if (i < 64) accs[i] = 0.0f;
  unsigned v0 = (unsigned)i, v1 = (unsigned)(1024+i);
  threefry2x32(v0, v1);
  xbuf0[i]        = bits_to_normal(v0);
  xbuf0[1024 + i] = bits_to_normal(v1);
}

// ---------------- bf16 convert helpers ----------------
__device__ __forceinline__ unsigned short f2bf(float f){
  unsigned u = __float_as_uint(f);
  unsigned r = (u + 0x7fffu + ((u>>16)&1u)) >> 16;
  return (unsigned short)r;
}
__device__ __forceinline__ unsigned pack2(float a, float b){
  return (unsigned)f2bf(a) | ((unsigned)f2bf(b) << 16);
}

// Wbf[j][k] = bf16(W[j][k]) : 784 x 2048
__global__ void conv_w(const float* __restrict__ W, unsigned short* __restrict__ Wbf){
  int i4 = (blockIdx.x*256 + threadIdx.x)*4;   // 1568 blocks
  float4 v = *(const float4*)(W + i4);
  uint2 p; p.x = pack2(v.x, v.y); p.y = pack2(v.z, v.w);
  *(uint2*)(Wbf + i4) = p;
}

// WTbf[k][j] = bf16(W[j][k]) : 2048 x 800 (j in [784,800) -> 0)
__global__ void transpose_w(const float* __restrict__ W, unsigned short* __restrict__ WTbf){
  __shared__ float tile[32][33];
  int k0 = blockIdx.x*32;       // 64 blocks in k
  int j0 = blockIdx.y*32;       // 25 blocks in j (800)
  int tx = threadIdx.x & 31, ty = threadIdx.x >> 5;   // 32 x 8
#pragma unroll
  for (int i=0;i<4;i++){
    int j = j0 + ty + 8*i;
    float v = (j < N_DIM) ? W[(size_t)j*M_DIM + k0 + tx] : 0.0f;
    tile[tx][ty+8*i] = v;
  }
  __syncthreads();
#pragma unroll
  for (int i=0;i<4;i++){
    int k = k0 + ty + 8*i;
    WTbf[(size_t)k*NPAD + j0 + tx] = f2bf(tile[ty+8*i][tx]);
  }
}

// ---------------- reductions ----------------
__global__ void sumsq_kernel(const float* __restrict__ v, int n, float* __restrict__ acc){
  __shared__ float red[256];
  int t = threadIdx.x;
  float s = 0.0f;
  for (int i = blockIdx.x*256 + t; i < n; i += gridDim.x*256){ float x = v[i]; s = fmaf(x,x,s); }
  red[t] = s; __syncthreads();
  for (int off=128; off>0; off>>=1){ if (t<off) red[t]+=red[t+off]; __syncthreads(); }
  if (t==0) atomicAdd(acc, red[0]);
}

// ---------------- power method (fp32, unchanged) ----------------
__global__ void pm_xwT(const float* __restrict__ x, const float* __restrict__ Wm,
                       float* __restrict__ tout){
  __shared__ float red[256];
  int t = threadIdx.x;
  float s = 0.0f;
  for (int k=t; k<M_DIM; k+=256){ float v = x[k]; s = fmaf(v,v,s); }
  red[t]=s; __syncthreads();
  for (int off=128; off>0; off>>=1){ if (t<off) red[t]+=red[t+off]; __syncthreads(); }
  float inv = 1.0f/sqrtf(red[0]);
  int wave = t>>6, lane = t&63;
  int j = blockIdx.x*4 + wave;
  const float* Wr = Wm + (size_t)j*M_DIM;
  float acc = 0.0f;
  for (int k=lane; k<M_DIM; k+=64) acc = fmaf(x[k], Wr[k], acc);
  for (int off=32; off>0; off>>=1) acc += __shfl_down(acc, off);
  if (lane==0) tout[j] = acc * inv;
}

__global__ void pm_tw(const float* __restrict__ tin, const float* __restrict__ Wm,
                      float* __restrict__ xout){
  int k = blockIdx.x*256 + threadIdx.x;
  float a0=0.f,a1=0.f,a2=0.f,a3=0.f;
  for (int j=0; j<N_DIM; j+=4){
    a0 = fmaf(tin[j+0], Wm[(size_t)(j+0)*M_DIM + k], a0);
    a1 = fmaf(tin[j+1], Wm[(size_t)(j+1)*M_DIM + k], a1);
    a2 = fmaf(tin[j+2], Wm[(size_t)(j+2)*M_DIM + k], a2);
    a3 = fmaf(tin[j+3], Wm[(size_t)(j+3)*M_DIM + k], a3);
  }
  xout[k] = (a0+a1)+(a2+a3);
}

// params: [0]=c, [1]=eta=1/c, [2]=lam/c, [3]=||Y||
__global__ void finish_power(const float* __restrict__ xfin, const float* __restrict__ accs,
                             float* __restrict__ params){
  __shared__ float red[256];
  int t = threadIdx.x;
  float s = 0.0f;
  for (int k=t; k<M_DIM; k+=256){ float v = xfin[k]; s = fmaf(v,v,s); }
  red[t]=s; __syncthreads();
  for (int off=128; off>0; off>>=1){ if (t<off) red[t]+=red[t+off]; __syncthreads(); }
  if (t==0){
    float c = sqrtf(red[0]);
    params[0] = c;
    params[1] = 1.0f/c;
    params[2] = 0.1f/c;
    params[3] = sqrtf(accs[0]);
  }
}

__device__ __forceinline__ float softthr(float v, float th){
  float a = fmaxf(fabsf(v) - th, 0.0f);
  return copysignf(a, v);
}

// ================= MFMA GEMM NT: C[i,j] = sum_k A[i,k]*W[j,k] =================
// A fp32 [8192 x 2048] (Z or Gamma). K=2048. grid (64,7), 256 threads.
// MODE 0: B from Wbf (bf16). R = A*W^T - Y -> Rbf (bf16, stride NPAD, pads zeroed),
//         accumulate ||R||^2 into nacc.
// MODE 1: B from Wf (fp32 original W, cvt at staging). X = A*W^T (fp32 out).
template<int MODE>
__global__ __launch_bounds__(256)
void mfma_nt(const float* __restrict__ A,
             const unsigned short* __restrict__ Wbf,
             const float* __restrict__ Wf,
             const float* __restrict__ Y,
             unsigned short* __restrict__ Rbf,
             float* __restrict__ X,
             float* __restrict__ nacc){
  __shared__ unsigned short As[128*40];   // row-major [m][k], stride 40 (80B, 2-way-free)
  __shared__ unsigned short Bs[128*40];   // [n][k]
  __shared__ float red4[4];
  const int t    = threadIdx.x;
  const int m0   = blockIdx.x*128, n0 = blockIdx.y*128;
  const int wave = t>>6, lane = t&63;
  const int wm   = wave>>1, wn = wave&1;
  const int quad = lane>>4, l15 = lane&15;
  const int sr   = t>>1;             // staging row 0..127
  const int skq  = (t&1)*16;         // staging k offset 0/16

  floatx4 acc[4][4];
#pragma unroll
  for (int i=0;i<4;i++)
#pragma unroll
    for (int j=0;j<4;j++) acc[i][j] = (floatx4)(0.0f);

  for (int k0=0; k0<M_DIM; k0+=32){
    // ---- stage A (fp32 -> bf16) ----
    {
      const float* ap = A + (size_t)(m0+sr)*M_DIM + k0 + skq;
      float4 v0 = *(const float4*)(ap+0);
      float4 v1 = *(const float4*)(ap+4);
      float4 v2 = *(const float4*)(ap+8);
      float4 v3 = *(const float4*)(ap+12);
      uint4 p0, p1;
      p0.x=pack2(v0.x,v0.y); p0.y=pack2(v0.z,v0.w); p0.z=pack2(v1.x,v1.y); p0.w=pack2(v1.z,v1.w);
      p1.x=pack2(v2.x,v2.y); p1.y=pack2(v2.z,v2.w); p1.z=pack2(v3.x,v3.y); p1.w=pack2(v3.z,v3.w);
      *(uint4*)&As[sr*40 + skq]     = p0;
      *(uint4*)&As[sr*40 + skq + 8] = p1;
    }
    // ---- stage B ----
    {
      int j = n0 + sr;
      if (MODE==0){
        uint4 p0 = make_uint4(0,0,0,0), p1 = make_uint4(0,0,0,0);
        if (j < N_DIM){
          const unsigned short* bp = Wbf + (size_t)j*M_DIM + k0 + skq;
          p0 = *(const uint4*)(bp+0);
          p1 = *(const uint4*)(bp+8);
        }
        *(uint4*)&Bs[sr*40 + skq]     = p0;
        *(uint4*)&Bs[sr*40 + skq + 8] = p1;
      } else {
        uint4 p0 = make_uint4(0,0,0,0), p1 = make_uint4(0,0,0,0);
        if (j < N_DIM){
          const float* bp = Wf + (size_t)j*M_DIM + k0 + skq;
          float4 v0 = *(const float4*)(bp+0);
          float4 v1 = *(const float4*)(bp+4);
          float4 v2 = *(const float4*)(bp+8);
          float4 v3 = *(const float4*)(bp+12);
          p0.x=pack2(v0.x,v0.y); p0.y=pack2(v0.z,v0.w); p0.z=pack2(v1.x,v1.y); p0.w=pack2(v1.z,v1.w);
          p1.x=pack2(v2.x,v2.y); p1.y=pack2(v2.z,v2.w); p1.z=pack2(v3.x,v3.y); p1.w=pack2(v3.z,v3.w);
        }
        *(uint4*)&Bs[sr*40 + skq]     = p0;
        *(uint4*)&Bs[sr*40 + skq + 8] = p1;
      }
    }
    __syncthreads();
    // ---- fragments + MFMA ----
    short8 af[4], bf[4];
#pragma unroll
    for (int ti=0; ti<4; ++ti)
      af[ti] = *(const short8*)&As[(wm*64 + ti*16 + l15)*40 + quad*8];
#pragma unroll
    for (int tj=0; tj<4; ++tj)
      bf[tj] = *(const short8*)&Bs[(wn*64 + tj*16 + l15)*40 + quad*8];
#pragma unroll
    for (int ti=0; ti<4; ++ti)
#pragma unroll
      for (int tj=0; tj<4; ++tj)
        acc[ti][tj] = __builtin_amdgcn_mfma_f32_16x16x32_bf16(af[ti], bf[tj], acc[ti][tj], 0, 0, 0);
    __syncthreads();
  }

  // ---- epilogue ----
  if (MODE==0){
    float ss = 0.0f;
#pragma unroll
    for (int ti=0; ti<4; ++ti){
#pragma unroll
      for (int tj=0; tj<4; ++tj){
#pragma unroll
        for (int r=0; r<4; ++r){
          int m = m0 + wm*64 + ti*16 + quad*4 + r;
          int n = n0 + wn*64 + tj*16 + l15;
          if (n < N_DIM){
            float rv = acc[ti][tj][r] - Y[(size_t)m*N_DIM + n];
            Rbf[(size_t)m*NPAD + n] = f2bf(rv);
            ss = fmaf(rv, rv, ss);
          } else if (n < NPAD){
            Rbf[(size_t)m*NPAD + n] = 0;
          }
        }
      }
    }
    // reduce ss: wave shuffle -> cross-wave LDS -> one atomic
    for (int off=32; off>0; off>>=1) ss += __shfl_down(ss, off);
    if (lane==0) red4[wave] = ss;
    __syncthreads();
    if (t==0) atomicAdd(nacc, red4[0]+red4[1]+red4[2]+red4[3]);
  } else {
#pragma unroll
    for (int ti=0; ti<4; ++ti){
#pragma unroll
      for (int tj=0; tj<4; ++tj){
#pragma unroll
        for (int r=0; r<4; ++r){
          int m = m0 + wm*64 + ti*16 + quad*4 + r;
          int n = n0 + wn*64 + tj*16 + l15;
          if (n < N_DIM) X[(size_t)m*N_DIM + n] = acc[ti][tj][r];
        }
      }
    }
  }
}

// ================= MFMA GEMM NN: G[i,k] = sum_j A[i,j]*W[j,k] =================
// B from WTbf [2048 x NPAD] bf16 (K-contiguous). K=NPAD (pads are zero). grid (64,16).
// MODE 0: A = Y fp32 (stride 784, k>=784 zero-filled). g=soft(eta*G,0.1); Gamma=Z=g.
// MODE 1: A = Rbf bf16 (stride NPAD). g=soft(Z-eta*G,lam/c); Z=g+mu*(g-Gamma); Gamma=g.
template<int MODE>
__global__ __launch_bounds__(256)
void mfma_nn(const float* __restrict__ Yin,
             const unsigned short* __restrict__ Rbf,
             const unsigned short* __restrict__ WTbf,
             float* __restrict__ Gamma,
             float* __restrict__ Z,
             const float* __restrict__ params,
             float mu){
  __shared__ unsigned short As[128*40];
  __shared__ unsigned short Bs[128*40];
  const int t    = threadIdx.x;
  const int m0   = blockIdx.x*128, n0 = blockIdx.y*128;
  const int wave = t>>6, lane = t&63;
  const int wm   = wave>>1, wn = wave&1;
  const int quad = lane>>4, l15 = lane&15;
  const int sr   = t>>1;
  const int skq  = (t&1)*16;

  floatx4 acc[4][4];
#pragma unroll
  for (int i=0;i<4;i++)
#pragma unroll
    for (int j=0;j<4;j++) acc[i][j] = (floatx4)(0.0f);

  for (int k0=0; k0<NPAD; k0+=32){
    // ---- stage A ----
    if (MODE==0){
      uint4 p0 = make_uint4(0,0,0,0), p1 = make_uint4(0,0,0,0);
      if (k0 + skq < N_DIM){   // 16-chunk fully valid (784 % 16 == 0)
        const float* ap = Yin + (size_t)(m0+sr)*N_DIM + k0 + skq;
        float4 v0 = *(const float4*)(ap+0);
        float4 v1 = *(const float4*)(ap+4);
        float4 v2 = *(const float4*)(ap+8);
        float4 v3 = *(const float4*)(ap+12);
        p0.x=pack2(v0.x,v0.y); p0.y=pack2(v0.z,v0.w); p0.z=pack2(v1.x,v1.y); p0.w=pack2(v1.z,v1.w);
        p1.x=pack2(v2.x,v2.y); p1.y=pack2(v2.z,v2.w); p1.z=pack2(v3.x,v3.y); p1.w=pack2(v3.z,v3.w);
      }
      *(uint4*)&As[sr*40 + skq]     = p0;
      *(uint4*)&As[sr*40 + skq + 8] = p1;
    } else {
      const unsigned short* ap = Rbf + (size_t)(m0+sr)*NPAD + k0 + skq;
      *(uint4*)&As[sr*40 + skq]     = *(const uint4*)(ap+0);
      *(uint4*)&As[sr*40 + skq + 8] = *(const uint4*)(ap+8);
    }
    // ---- stage B (always bf16 WTbf) ----
    {
      const unsigned short* bp = WTbf + (size_t)(n0+sr)*NPAD + k0 + skq;
      *(uint4*)&Bs[sr*40 + skq]     = *(const uint4*)(bp+0);
      *(uint4*)&Bs[sr*40 + skq + 8] = *(const uint4*)(bp+8);
    }
    __syncthreads();
    short8 af[4], bfr[4];
#pragma unroll
    for (int ti=0; ti<4; ++ti)
      af[ti] = *(const short8*)&As[(wm*64 + ti*16 + l15)*40 + quad*8];
#pragma unroll
    for (int tj=0; tj<4; ++tj)
      bfr[tj] = *(const short8*)&Bs[(wn*64 + tj*16 + l15)*40 + quad*8];
#pragma unroll
    for (int ti=0; ti<4; ++ti)
#pragma unroll
      for (int tj=0; tj<4; ++tj)
        acc[ti][tj] = __builtin_amdgcn_mfma_f32_16x16x32_bf16(af[ti], bfr[tj], acc[ti][tj], 0, 0, 0);
    __syncthreads();
  }

  const float eta  = params[1];
  const float lamc = params[2];
#pragma unroll
  for (int ti=0; ti<4; ++ti){
#pragma unroll
    for (int tj=0; tj<4; ++tj){
#pragma unroll
      for (int r=0; r<4; ++r){
        int m = m0 + wm*64 + ti*16 + quad*4 + r;
        int n = n0 + wn*64 + tj*16 + l15;
        size_t idx = (size_t)m*M_DIM + n;
        if (MODE==0){
          float g = softthr(eta*acc[ti][tj][r], 0.1f);
          Gamma[idx] = g;
          Z[idx]     = g;
        } else {
          float zv = Z[idx];
          float g  = softthr(zv - eta*acc[ti][tj][r], lamc);
          float go = Gamma[idx];
          Gamma[idx] = g;
          Z[idx]     = g + mu*(g - go);
        }
      }
    }
  }
}

__global__ void norms_finalize(const float* __restrict__ nacc, const float* __restrict__ params,
                               float* __restrict__ out){
  int i = threadIdx.x;
  if (i < NITER) out[i] = sqrtf(nacc[i]) / params[3];
}

extern "C" void kernel_launch(void* const* d_in, const int* in_sizes, int n_in,
                              void* d_out, int out_size, void* d_ws, size_t ws_size,
                              hipStream_t stream){
  const float* Y  = (const float*)d_in[0];
  const float* W  = (const float*)d_in[1];
  float* out      = (float*)d_out;
  float* X        = out;                 // [8192x784] fp32 — also scratch until final GEMM
  float* Gamma    = out + XSZ;           // [8192x2048] fp32
  float* norms    = out + XSZ + GSZ;     // [50]
  float* ws       = (float*)d_ws;
  float* Z        = ws;                  // [8192x2048] fp32 (64 MB — round-1-proven footprint)
  float* xb0      = ws + GSZ;
  float* xb1      = xb0 + M_DIM;
  float* tb       = xb1 + M_DIM;
  float* params   = tb + N_DIM;
  float* accs     = params + 8;          // accs[0]=||Y||^2, accs[1..50]=per-iter ||R||^2

  // bf16 scratch lives in the X region of d_out (19.6 MB <= 25.7 MB), dead before X write.
  unsigned short* Rbf  = (unsigned short*)out;             // [8192 x 800]
  unsigned short* Wbf  = Rbf + (size_t)B_DIM*NPAD;         // [784 x 2048]
  unsigned short* WTbf = Wbf + (size_t)N_DIM*M_DIM;        // [2048 x 800]

  setup_kernel<<<dim3(1), dim3(1024), 0, stream>>>(xb0, accs);
  sumsq_kernel<<<dim3(512), dim3(256), 0, stream>>>(Y, XSZ, accs);
  conv_w      <<<dim3(1568), dim3(256), 0, stream>>>(W, Wbf);
  transpose_w <<<dim3(64,25), dim3(256), 0, stream>>>(W, WTbf);

  float* xa = xb0; float* xc = xb1;
  for (int it=0; it<PITER; ++it){
    pm_xwT<<<dim3(196), dim3(256), 0, stream>>>(xa, W, tb);
    pm_tw <<<dim3(8),   dim3(256), 0, stream>>>(tb, W, xc);
    float* tmp = xa; xa = xc; xc = tmp;
  }
  finish_power<<<dim3(1), dim3(256), 0, stream>>>(xa, accs, params);

  // Gamma0 = soft(eta*(Y@W), 0.1); Z0 = Gamma0
  mfma_nn<0><<<dim3(64,16), dim3(256), 0, stream>>>(Y, nullptr, WTbf, Gamma, Z, params, 0.0f);

  float tcur = 1.0f;
  for (int it=0; it<NITER; ++it){
    mfma_nt<0><<<dim3(64,7), dim3(256), 0, stream>>>(Z, Wbf, nullptr, Y, Rbf, nullptr, accs + 1 + it);
    float tsq = tcur*tcur;
    float tn  = (1.0f + sqrtf(1.0f + 4.0f*tsq)) / 2.0f;
    float mu  = (tcur - 1.0f) / tn;
    tcur = tn;
    mfma_nn<1><<<dim3(64,16), dim3(256), 0, stream>>>(nullptr, Rbf, WTbf, Gamma, Z, params, mu);
  }

  // X = Gamma @ W^T  (B staged from fp32 W to avoid racing the X region)
  mfma_nt<1><<<dim3(64,7), dim3(256), 0, stream>>>(Gamma, nullptr, W, Y, nullptr, X, nullptr);
  norms_finalize<<<dim3(1), dim3(64), 0, stream>>>(accs + 1, params, norms);
}

// Round 4
// 12314.661 us; speedup vs baseline: 3.4683x; 1.0648x over previous
//
#include <hip/hip_runtime.h>
#include <math.h>

#define B_DIM   8192
#define N_DIM   784
#define NPAD    800          // 25*32, K/N pad for the NN GEMM / Rbf
#define NROWS_W 896          // 7*128, row-pad for Wbf (NT B operand)
#define M_DIM   2048
#define XSZ     (B_DIM*N_DIM)
#define GSZ     (B_DIM*M_DIM)
#define NITER   50
#define PITER   100

typedef __attribute__((ext_vector_type(8))) short short8;
typedef __attribute__((ext_vector_type(4))) float floatx4;

// ---------------- async global->LDS (16B per lane, wave-uniform LDS base) ----------------
__device__ __forceinline__ void async_ld16(const unsigned short* g, unsigned short* l){
  __builtin_amdgcn_global_load_lds(
      (const __attribute__((address_space(1))) unsigned int*)g,
      (__attribute__((address_space(3))) unsigned int*)l,
      16, 0, 0);
}

// ---------------- threefry + erfinv (reproduce jax.random.normal(key(1),(1,2048))) ------------
__device__ __forceinline__ unsigned rotl32(unsigned x, int d){ return (x<<d)|(x>>(32-d)); }

__device__ void threefry2x32(unsigned& v0, unsigned& v1){
  const unsigned ks0=0u, ks1=1u, ks2=0x1BD11BDBu;
  unsigned x0=v0+ks0, x1=v1+ks1;
#define RND(R) { x0+=x1; x1=rotl32(x1,R); x1^=x0; }
  RND(13) RND(15) RND(26) RND(6)
  x0+=ks1; x1+=ks2+1u;
  RND(17) RND(29) RND(16) RND(24)
  x0+=ks2; x1+=ks0+2u;
  RND(13) RND(15) RND(26) RND(6)
  x0+=ks0; x1+=ks1+3u;
  RND(17) RND(29) RND(16) RND(24)
  x0+=ks1; x1+=ks2+4u;
  RND(13) RND(15) RND(26) RND(6)
  x0+=ks2; x1+=ks0+5u;
#undef RND
  v0=x0; v1=x1;
}

__device__ float erfinv_f(float x){
  float w = -logf((1.0f-x)*(1.0f+x));
  float p;
  if (w < 5.0f){
    w -= 2.5f;
    p = 2.81022636e-08f;
    p = fmaf(p,w, 3.43273939e-07f);
    p = fmaf(p,w,-3.5233877e-06f);
    p = fmaf(p,w,-4.39150654e-06f);
    p = fmaf(p,w, 0.00021858087f);
    p = fmaf(p,w,-0.00125372503f);
    p = fmaf(p,w,-0.00417768164f);
    p = fmaf(p,w, 0.246640727f);
    p = fmaf(p,w, 1.50140941f);
  } else {
    w = sqrtf(w) - 3.0f;
    p = -0.000200214257f;
    p = fmaf(p,w, 0.000100950558f);
    p = fmaf(p,w, 0.00134934322f);
    p = fmaf(p,w,-0.00367342844f);
    p = fmaf(p,w, 0.00573950773f);
    p = fmaf(p,w,-0.0076224613f);
    p = fmaf(p,w, 0.00943887047f);
    p = fmaf(p,w, 1.00167406f);
    p = fmaf(p,w, 2.83297682f);
  }
  return p*x;
}

__device__ float bits_to_normal(unsigned b){
  unsigned fb = (b>>9) | 0x3f800000u;
  float u01 = __uint_as_float(fb) - 1.0f;
  const float lo = -0.99999994f;
  float u = u01*(1.0f - lo) + lo;
  u = fmaxf(lo, u);
  return 1.41421356237f * erfinv_f(u);
}

__global__ void setup_kernel(float* __restrict__ xbuf0, float* __restrict__ accs){
  int i = threadIdx.x;   // 1024 threads
  if (i < 64) accs[i] = 0.0f;
  unsigned v0 = (unsigned)i, v1 = (unsigned)(1024+i);
  threefry2x32(v0, v1);
  xbuf0[i]        = bits_to_normal(v0);
  xbuf0[1024 + i] = bits_to_normal(v1);
}

// ---------------- bf16 convert helpers ----------------
__device__ __forceinline__ unsigned short f2bf(float f){
  unsigned u = __float_as_uint(f);
  unsigned r = (u + 0x7fffu + ((u>>16)&1u)) >> 16;
  return (unsigned short)r;
}
__device__ __forceinline__ unsigned pack2(float a, float b){
  return (unsigned)f2bf(a) | ((unsigned)f2bf(b) << 16);
}
__device__ __forceinline__ float bf2f(unsigned short s){
  return __uint_as_float(((unsigned)s) << 16);
}

// Wbf[j][k] = bf16(W[j][k]) : 896 x 2048, rows >=784 zeroed
__global__ void conv_w(const float* __restrict__ W, unsigned short* __restrict__ Wbf){
  int i4 = (blockIdx.x*256 + threadIdx.x)*4;   // over 896*2048 -> 1792 blocks
  int row = i4 >> 11;
  uint2 p = make_uint2(0,0);
  if (row < N_DIM){
    float4 v = *(const float4*)(W + (size_t)row*M_DIM + (i4 & 2047));
    p.x = pack2(v.x, v.y); p.y = pack2(v.z, v.w);
  }
  *(uint2*)(Wbf + i4) = p;
}

// Ybf[i][j] = bf16(Y[i][j]) : 8192 x 800, cols >=784 zeroed  (stored into Rbf buffer)
__global__ void conv_y(const float* __restrict__ Y, unsigned short* __restrict__ Ybf){
  int row = blockIdx.x;          // 8192 blocks, thread t -> cols [4t,4t+4)
  int c4 = threadIdx.x*4;
  if (c4 >= NPAD) return;
  uint2 p = make_uint2(0,0);
  if (c4 < N_DIM){
    float4 v = *(const float4*)(Y + (size_t)row*N_DIM + c4);
    p.x = pack2(v.x, v.y); p.y = pack2(v.z, v.w);
  }
  *(uint2*)(Ybf + (size_t)row*NPAD + c4) = p;
}

// WTbf[k][j] = bf16(W[j][k]) : 2048 x 800 (j in [784,800) -> 0)
__global__ void transpose_w(const float* __restrict__ W, unsigned short* __restrict__ WTbf){
  __shared__ float tile[32][33];
  int k0 = blockIdx.x*32;       // 64 blocks in k
  int j0 = blockIdx.y*32;       // 25 blocks in j (800)
  int tx = threadIdx.x & 31, ty = threadIdx.x >> 5;   // 32 x 8
#pragma unroll
  for (int i=0;i<4;i++){
    int j = j0 + ty + 8*i;
    float v = (j < N_DIM) ? W[(size_t)j*M_DIM + k0 + tx] : 0.0f;
    tile[tx][ty+8*i] = v;
  }
  __syncthreads();
#pragma unroll
  for (int i=0;i<4;i++){
    int k = k0 + ty + 8*i;
    WTbf[(size_t)k*NPAD + j0 + tx] = f2bf(tile[ty+8*i][tx]);
  }
}

// ---------------- reductions ----------------
__global__ void sumsq_kernel(const float* __restrict__ v, int n, float* __restrict__ acc){
  __shared__ float red[256];
  int t = threadIdx.x;
  float s = 0.0f;
  for (int i = blockIdx.x*256 + t; i < n; i += gridDim.x*256){ float x = v[i]; s = fmaf(x,x,s); }
  red[t] = s; __syncthreads();
  for (int off=128; off>0; off>>=1){ if (t<off) red[t]+=red[t+off]; __syncthreads(); }
  if (t==0) atomicAdd(acc, red[0]);
}

// ---------------- power method (fp32, proven) ----------------
__global__ void pm_xwT(const float* __restrict__ x, const float* __restrict__ Wm,
                       float* __restrict__ tout){
  __shared__ float red[256];
  int t = threadIdx.x;
  float s = 0.0f;
  for (int k=t; k<M_DIM; k+=256){ float v = x[k]; s = fmaf(v,v,s); }
  red[t]=s; __syncthreads();
  for (int off=128; off>0; off>>=1){ if (t<off) red[t]+=red[t+off]; __syncthreads(); }
  float inv = 1.0f/sqrtf(red[0]);
  int wave = t>>6, lane = t&63;
  int j = blockIdx.x*4 + wave;
  const float* Wr = Wm + (size_t)j*M_DIM;
  float acc = 0.0f;
  for (int k=lane; k<M_DIM; k+=64) acc = fmaf(x[k], Wr[k], acc);
  for (int off=32; off>0; off>>=1) acc += __shfl_down(acc, off);
  if (lane==0) tout[j] = acc * inv;
}

__global__ void pm_tw(const float* __restrict__ tin, const float* __restrict__ Wm,
                      float* __restrict__ xout){
  int k = blockIdx.x*256 + threadIdx.x;
  float a0=0.f,a1=0.f,a2=0.f,a3=0.f;
  for (int j=0; j<N_DIM; j+=4){
    a0 = fmaf(tin[j+0], Wm[(size_t)(j+0)*M_DIM + k], a0);
    a1 = fmaf(tin[j+1], Wm[(size_t)(j+1)*M_DIM + k], a1);
    a2 = fmaf(tin[j+2], Wm[(size_t)(j+2)*M_DIM + k], a2);
    a3 = fmaf(tin[j+3], Wm[(size_t)(j+3)*M_DIM + k], a3);
  }
  xout[k] = (a0+a1)+(a2+a3);
}

// params: [0]=c, [1]=eta=1/c, [2]=lam/c, [3]=||Y||
__global__ void finish_power(const float* __restrict__ xfin, const float* __restrict__ accs,
                             float* __restrict__ params){
  __shared__ float red[256];
  int t = threadIdx.x;
  float s = 0.0f;
  for (int k=t; k<M_DIM; k+=256){ float v = xfin[k]; s = fmaf(v,v,s); }
  red[t]=s; __syncthreads();
  for (int off=128; off>0; off>>=1){ if (t<off) red[t]+=red[t+off]; __syncthreads(); }
  if (t==0){
    float c = sqrtf(red[0]);
    params[0] = c;
    params[1] = 1.0f/c;
    params[2] = 0.1f/c;
    params[3] = sqrtf(accs[0]);
  }
}

__device__ __forceinline__ float softthr(float v, float th){
  float a = fmaxf(fabsf(v) - th, 0.0f);
  return copysignf(a, v);
}

// ================= MFMA GEMM NT: C[i,j] = sum_k A[i,k]*B[j,k] =================
// A = Zhi bf16 [8192 x 2048] (async). grid (64,7), 256 threads.
// MODE 0: B = Wbf bf16 (async).  R = A*B^T - Y -> Rbf (bf16, stride NPAD, pads zeroed),
//         ||R||^2 -> nacc.
// MODE 1: B staged manually from fp32 W (Wbf lives in the X region being written).
//         X = A*B^T (fp32 out; A holds bf16 of final Gamma).
template<int MODE>
__global__ __launch_bounds__(256)
void mfma_nt(const unsigned short* __restrict__ Abf,
             const unsigned short* __restrict__ Bbf,
             const float* __restrict__ Wf,
             const float* __restrict__ Y,
             unsigned short* __restrict__ Rbf,
             float* __restrict__ X,
             float* __restrict__ nacc){
  __shared__ unsigned short As[128*32];   // [m][k] unpadded (global_load_lds layout)
  __shared__ unsigned short Bs[128*32];   // [n][k]
  __shared__ float red4[4];
  const int t    = threadIdx.x;
  const int m0   = blockIdx.x*128, n0 = blockIdx.y*128;
  const int wave = t>>6, lane = t&63;
  const int wm   = wave>>1, wn = wave&1;
  const int quad = lane>>4, l15 = lane&15;
  const int ch0  = wave*2;
  const int lrow = lane>>2;
  const int lk   = (lane&3)*8;
  const int sr   = t>>1;          // manual staging row (MODE 1)
  const int skq  = (t&1)*16;

  floatx4 acc[4][4];
#pragma unroll
  for (int i=0;i<4;i++)
#pragma unroll
    for (int j=0;j<4;j++) acc[i][j] = (floatx4)(0.0f);

  for (int k0=0; k0<M_DIM; k0+=32){
#pragma unroll
    for (int c=0; c<2; ++c){
      int chunk = ch0 + c;
      async_ld16(Abf + (size_t)(m0 + chunk*16 + lrow)*M_DIM + k0 + lk, &As[chunk*512]);
    }
    if (MODE==0){
#pragma unroll
      for (int c=0; c<2; ++c){
        int chunk = ch0 + c;
        async_ld16(Bbf + (size_t)(n0 + chunk*16 + lrow)*M_DIM + k0 + lk, &Bs[chunk*512]);
      }
    } else {
      int j = n0 + sr;
      uint4 p0 = make_uint4(0,0,0,0), p1 = make_uint4(0,0,0,0);
      if (j < N_DIM){
        const float* bp = Wf + (size_t)j*M_DIM + k0 + skq;
        float4 v0 = *(const float4*)(bp+0);
        float4 v1 = *(const float4*)(bp+4);
        float4 v2 = *(const float4*)(bp+8);
        float4 v3 = *(const float4*)(bp+12);
        p0.x=pack2(v0.x,v0.y); p0.y=pack2(v0.z,v0.w); p0.z=pack2(v1.x,v1.y); p0.w=pack2(v1.z,v1.w);
        p1.x=pack2(v2.x,v2.y); p1.y=pack2(v2.z,v2.w); p1.z=pack2(v3.x,v3.y); p1.w=pack2(v3.z,v3.w);
      }
      *(uint4*)&Bs[sr*32 + skq]     = p0;
      *(uint4*)&Bs[sr*32 + skq + 8] = p1;
    }
    __syncthreads();
    short8 af[4], bfr[4];
#pragma unroll
    for (int ti=0; ti<4; ++ti)
      af[ti] = *(const short8*)&As[(wm*64 + ti*16 + l15)*32 + quad*8];
#pragma unroll
    for (int tj=0; tj<4; ++tj)
      bfr[tj] = *(const short8*)&Bs[(wn*64 + tj*16 + l15)*32 + quad*8];
#pragma unroll
    for (int ti=0; ti<4; ++ti)
#pragma unroll
      for (int tj=0; tj<4; ++tj)
        acc[ti][tj] = __builtin_amdgcn_mfma_f32_16x16x32_bf16(af[ti], bfr[tj], acc[ti][tj], 0, 0, 0);
    __syncthreads();
  }

  if (MODE==0){
    float ss = 0.0f;
#pragma unroll
    for (int ti=0; ti<4; ++ti){
#pragma unroll
      for (int tj=0; tj<4; ++tj){
#pragma unroll
        for (int r=0; r<4; ++r){
          int m = m0 + wm*64 + ti*16 + quad*4 + r;
          int n = n0 + wn*64 + tj*16 + l15;
          if (n < N_DIM){
            float rv = acc[ti][tj][r] - Y[(size_t)m*N_DIM + n];
            Rbf[(size_t)m*NPAD + n] = f2bf(rv);
            ss = fmaf(rv, rv, ss);
          } else if (n < NPAD){
            Rbf[(size_t)m*NPAD + n] = 0;
          }
        }
      }
    }
    for (int off=32; off>0; off>>=1) ss += __shfl_down(ss, off);
    if (lane==0) red4[wave] = ss;
    __syncthreads();
    if (t==0) atomicAdd(nacc, red4[0]+red4[1]+red4[2]+red4[3]);
  } else {
#pragma unroll
    for (int ti=0; ti<4; ++ti){
#pragma unroll
      for (int tj=0; tj<4; ++tj){
#pragma unroll
        for (int r=0; r<4; ++r){
          int m = m0 + wm*64 + ti*16 + quad*4 + r;
          int n = n0 + wn*64 + tj*16 + l15;
          if (n < N_DIM) X[(size_t)m*N_DIM + n] = acc[ti][tj][r];
        }
      }
    }
  }
}

// ================= MFMA GEMM NN: G[i,n] = sum_j A[i,j]*WT[n,j] ==========
// A = Rbf/Ybf [8192 x 800] (async), B = WTbf [2048 x 800] (async). grid (64,16).
// State: z kept as hi/lo bf16 pair (~16-bit mantissa); Gamma fp32 (graded output).
// MODE 0 (init, A=Ybf): g=soft(eta*G,0.1); Gamma=g; z=g -> hi/lo.
// MODE 1 (iter, A=Rbf): z=hi+lo; g=soft(z-eta*G,lam/c); zn=g+mu*(g-go); store hi/lo.
// MODE 2 (last iter):   g=soft(z-eta*G,lam/c); Gamma=g; Zhi=bf16(g) [A for final X GEMM].
template<int MODE>
__global__ __launch_bounds__(256)
void mfma_nn(const unsigned short* __restrict__ Abf,
             const unsigned short* __restrict__ WTbf,
             float* __restrict__ Gamma,
             unsigned short* __restrict__ Zhi,
             unsigned short* __restrict__ Zlo,
             const float* __restrict__ params,
             float mu){
  __shared__ unsigned short As[128*32];
  __shared__ unsigned short Bs[128*32];
  const int t    = threadIdx.x;
  const int m0   = blockIdx.x*128, n0 = blockIdx.y*128;
  const int wave = t>>6, lane = t&63;
  const int wm   = wave>>1, wn = wave&1;
  const int quad = lane>>4, l15 = lane&15;
  const int ch0  = wave*2;
  const int lrow = lane>>2;
  const int lk   = (lane&3)*8;

  floatx4 acc[4][4];
#pragma unroll
  for (int i=0;i<4;i++)
#pragma unroll
    for (int j=0;j<4;j++) acc[i][j] = (floatx4)(0.0f);

  for (int k0=0; k0<NPAD; k0+=32){
#pragma unroll
    for (int c=0; c<2; ++c){
      int chunk = ch0 + c;
      async_ld16(Abf  + (size_t)(m0 + chunk*16 + lrow)*NPAD + k0 + lk, &As[chunk*512]);
      async_ld16(WTbf + (size_t)(n0 + chunk*16 + lrow)*NPAD + k0 + lk, &Bs[chunk*512]);
    }
    __syncthreads();
    short8 af[4], bfr[4];
#pragma unroll
    for (int ti=0; ti<4; ++ti)
      af[ti] = *(const short8*)&As[(wm*64 + ti*16 + l15)*32 + quad*8];
#pragma unroll
    for (int tj=0; tj<4; ++tj)
      bfr[tj] = *(const short8*)&Bs[(wn*64 + tj*16 + l15)*32 + quad*8];
#pragma unroll
    for (int ti=0; ti<4; ++ti)
#pragma unroll
      for (int tj=0; tj<4; ++tj)
        acc[ti][tj] = __builtin_amdgcn_mfma_f32_16x16x32_bf16(af[ti], bfr[tj], acc[ti][tj], 0, 0, 0);
    __syncthreads();
  }

  const float eta  = params[1];
  const float lamc = params[2];
#pragma unroll
  for (int ti=0; ti<4; ++ti){
#pragma unroll
    for (int tj=0; tj<4; ++tj){
#pragma unroll
      for (int r=0; r<4; ++r){
        int m = m0 + wm*64 + ti*16 + quad*4 + r;
        int n = n0 + wn*64 + tj*16 + l15;
        size_t idx = (size_t)m*M_DIM + n;
        if (MODE==0){
          float g = softthr(eta*acc[ti][tj][r], 0.1f);
          Gamma[idx] = g;
          unsigned short h = f2bf(g);
          Zhi[idx] = h;
          Zlo[idx] = f2bf(g - bf2f(h));
        } else {
          float zv = bf2f(Zhi[idx]) + bf2f(Zlo[idx]);
          float g  = softthr(zv - eta*acc[ti][tj][r], lamc);
          float go = Gamma[idx];
          Gamma[idx] = g;
          if (MODE==2){
            Zhi[idx] = f2bf(g);
          } else {
            float zn = g + mu*(g - go);
            unsigned short h = f2bf(zn);
            Zhi[idx] = h;
            Zlo[idx] = f2bf(zn - bf2f(h));
          }
        }
      }
    }
  }
}

__global__ void norms_finalize(const float* __restrict__ nacc, const float* __restrict__ params,
                               float* __restrict__ out){
  int i = threadIdx.x;
  if (i < NITER) out[i] = sqrtf(nacc[i]) / params[3];
}

extern "C" void kernel_launch(void* const* d_in, const int* in_sizes, int n_in,
                              void* d_out, int out_size, void* d_ws, size_t ws_size,
                              hipStream_t stream){
  const float* Y  = (const float*)d_in[0];
  const float* W  = (const float*)d_in[1];
  float* out      = (float*)d_out;
  float* X        = out;                 // [8192x784] fp32 (written last)
  float* Gamma    = out + XSZ;           // [8192x2048] fp32
  float* norms    = out + XSZ + GSZ;     // [50]

  // ---- ws: exactly 64 MiB (round-1-proven budget): z state as hi/lo bf16 pair ----
  unsigned short* Zhi = (unsigned short*)d_ws;           // [8192 x 2048]  33.5 MB
  unsigned short* Zlo = Zhi + (size_t)B_DIM*M_DIM;       // [8192 x 2048]  33.5 MB

  // ---- bf16 operand scratch + small fp32 scratch in the X region of d_out (dead before X) ----
  unsigned short* Rbf  = (unsigned short*)out;           // [8192 x 800]  13.1 MB (holds Ybf at init)
  unsigned short* Wbf  = Rbf + (size_t)B_DIM*NPAD;       // [896 x 2048]   3.7 MB
  unsigned short* WTbf = Wbf + (size_t)NROWS_W*M_DIM;    // [2048 x 800]   3.3 MB
  float* fsc    = (float*)(WTbf + (size_t)M_DIM*NPAD);   // ~20 KB, still inside X region
  float* xb0    = fsc;
  float* xb1    = xb0 + M_DIM;
  float* tb     = xb1 + M_DIM;
  float* params = tb + N_DIM;
  float* accs   = params + 8;            // accs[0]=||Y||^2, accs[1..50]=per-iter ||R||^2

  setup_kernel<<<dim3(1), dim3(1024), 0, stream>>>(xb0, accs);
  sumsq_kernel<<<dim3(512), dim3(256), 0, stream>>>(Y, XSZ, accs);
  conv_w      <<<dim3(1792), dim3(256), 0, stream>>>(W, Wbf);
  conv_y      <<<dim3(B_DIM), dim3(256), 0, stream>>>(Y, Rbf);   // Rbf := Ybf for init GEMM
  transpose_w <<<dim3(64,25), dim3(256), 0, stream>>>(W, WTbf);

  float* xa = xb0; float* xc = xb1;
  for (int it=0; it<PITER; ++it){
    pm_xwT<<<dim3(196), dim3(256), 0, stream>>>(xa, W, tb);
    pm_tw <<<dim3(8),   dim3(256), 0, stream>>>(tb, W, xc);
    float* tmp = xa; xa = xc; xc = tmp;
  }
  finish_power<<<dim3(1), dim3(256), 0, stream>>>(xa, accs, params);

  // Gamma0 = soft(eta*(Y@W), 0.1); z0 = Gamma0 -> hi/lo
  mfma_nn<0><<<dim3(64,16), dim3(256), 0, stream>>>(Rbf, WTbf, Gamma, Zhi, Zlo, params, 0.0f);

  float tcur = 1.0f;
  for (int it=0; it<NITER; ++it){
    mfma_nt<0><<<dim3(64,7), dim3(256), 0, stream>>>(Zhi, Wbf, nullptr, Y, Rbf, nullptr, accs + 1 + it);
    float tsq = tcur*tcur;
    float tn  = (1.0f + sqrtf(1.0f + 4.0f*tsq)) / 2.0f;
    float mu  = (tcur - 1.0f) / tn;
    tcur = tn;
    if (it < NITER-1)
      mfma_nn<1><<<dim3(64,16), dim3(256), 0, stream>>>(Rbf, WTbf, Gamma, Zhi, Zlo, params, mu);
    else
      mfma_nn<2><<<dim3(64,16), dim3(256), 0, stream>>>(Rbf, WTbf, Gamma, Zhi, Zlo, params, mu);
  }

  // norms BEFORE the final X GEMM (X write covers the scratch tail holding accs/params)
  norms_finalize<<<dim3(1), dim3(64), 0, stream>>>(accs + 1, params, norms);

  // X = Gamma @ W^T  (Zhi holds bf16 Gamma; B staged from fp32 W — Wbf is in the X region)
  mfma_nt<1><<<dim3(64,7), dim3(256), 0, stream>>>(Zhi, nullptr, W, nullptr, nullptr, X, nullptr);
}

// Round 5
// 9634.943 us; speedup vs baseline: 4.4329x; 1.2781x over previous
//
#include <hip/hip_runtime.h>
#include <math.h>

#define B_DIM   8192
#define N_DIM   784
#define NPAD    800          // 25*32, K/N pad for the NN GEMM / Rbf
#define NROWS_W 896          // 7*128, row-pad for Wbf (NT B operand)
#define M_DIM   2048
#define XSZ     (B_DIM*N_DIM)
#define GSZ     (B_DIM*M_DIM)
#define NITER   50
#define PITER   100

typedef __attribute__((ext_vector_type(8))) short short8;
typedef __attribute__((ext_vector_type(4))) float floatx4;

// ---------------- async global->LDS (16B per lane, wave-uniform LDS base) ----------------
__device__ __forceinline__ void async_ld16(const unsigned short* g, unsigned short* l){
  __builtin_amdgcn_global_load_lds(
      (const __attribute__((address_space(1))) unsigned int*)g,
      (__attribute__((address_space(3))) unsigned int*)l,
      16, 0, 0);
}

// ---------------- threefry + erfinv (reproduce jax.random.normal(key(1),(1,2048))) ------------
__device__ __forceinline__ unsigned rotl32(unsigned x, int d){ return (x<<d)|(x>>(32-d)); }

__device__ void threefry2x32(unsigned& v0, unsigned& v1){
  const unsigned ks0=0u, ks1=1u, ks2=0x1BD11BDBu;
  unsigned x0=v0+ks0, x1=v1+ks1;
#define RND(R) { x0+=x1; x1=rotl32(x1,R); x1^=x0; }
  RND(13) RND(15) RND(26) RND(6)
  x0+=ks1; x1+=ks2+1u;
  RND(17) RND(29) RND(16) RND(24)
  x0+=ks2; x1+=ks0+2u;
  RND(13) RND(15) RND(26) RND(6)
  x0+=ks0; x1+=ks1+3u;
  RND(17) RND(29) RND(16) RND(24)
  x0+=ks1; x1+=ks2+4u;
  RND(13) RND(15) RND(26) RND(6)
  x0+=ks2; x1+=ks0+5u;
#undef RND
  v0=x0; v1=x1;
}

__device__ float erfinv_f(float x){
  float w = -logf((1.0f-x)*(1.0f+x));
  float p;
  if (w < 5.0f){
    w -= 2.5f;
    p = 2.81022636e-08f;
    p = fmaf(p,w, 3.43273939e-07f);
    p = fmaf(p,w,-3.5233877e-06f);
    p = fmaf(p,w,-4.39150654e-06f);
    p = fmaf(p,w, 0.00021858087f);
    p = fmaf(p,w,-0.00125372503f);
    p = fmaf(p,w,-0.00417768164f);
    p = fmaf(p,w, 0.246640727f);
    p = fmaf(p,w, 1.50140941f);
  } else {
    w = sqrtf(w) - 3.0f;
    p = -0.000200214257f;
    p = fmaf(p,w, 0.000100950558f);
    p = fmaf(p,w, 0.00134934322f);
    p = fmaf(p,w,-0.00367342844f);
    p = fmaf(p,w, 0.00573950773f);
    p = fmaf(p,w,-0.0076224613f);
    p = fmaf(p,w, 0.00943887047f);
    p = fmaf(p,w, 1.00167406f);
    p = fmaf(p,w, 2.83297682f);
  }
  return p*x;
}

__device__ float bits_to_normal(unsigned b){
  unsigned fb = (b>>9) | 0x3f800000u;
  float u01 = __uint_as_float(fb) - 1.0f;
  const float lo = -0.99999994f;
  float u = u01*(1.0f - lo) + lo;
  u = fmaxf(lo, u);
  return 1.41421356237f * erfinv_f(u);
}

__global__ void setup_kernel(float* __restrict__ xbuf0, float* __restrict__ accs){
  int i = threadIdx.x;   // 1024 threads
  if (i < 64) accs[i] = 0.0f;
  unsigned v0 = (unsigned)i, v1 = (unsigned)(1024+i);
  threefry2x32(v0, v1);
  xbuf0[i]        = bits_to_normal(v0);
  xbuf0[1024 + i] = bits_to_normal(v1);
}

// ---------------- bf16 convert helpers ----------------
__device__ __forceinline__ unsigned short f2bf(float f){
  unsigned u = __float_as_uint(f);
  unsigned r = (u + 0x7fffu + ((u>>16)&1u)) >> 16;
  return (unsigned short)r;
}
__device__ __forceinline__ unsigned pack2(float a, float b){
  return (unsigned)f2bf(a) | ((unsigned)f2bf(b) << 16);
}
__device__ __forceinline__ float bf2f(unsigned short s){
  return __uint_as_float(((unsigned)s) << 16);
}

// Wbf[j][k] = bf16(W[j][k]) : 896 x 2048, rows >=784 zeroed
__global__ void conv_w(const float* __restrict__ W, unsigned short* __restrict__ Wbf){
  int i4 = (blockIdx.x*256 + threadIdx.x)*4;   // over 896*2048 -> 1792 blocks
  int row = i4 >> 11;
  uint2 p = make_uint2(0,0);
  if (row < N_DIM){
    float4 v = *(const float4*)(W + (size_t)row*M_DIM + (i4 & 2047));
    p.x = pack2(v.x, v.y); p.y = pack2(v.z, v.w);
  }
  *(uint2*)(Wbf + i4) = p;
}

// Ybf[i][j] = bf16(Y[i][j]) : 8192 x 800, cols >=784 zeroed  (stored into Rbf buffer)
__global__ void conv_y(const float* __restrict__ Y, unsigned short* __restrict__ Ybf){
  int row = blockIdx.x;          // 8192 blocks, thread t -> cols [4t,4t+4)
  int c4 = threadIdx.x*4;
  if (c4 >= NPAD) return;
  uint2 p = make_uint2(0,0);
  if (c4 < N_DIM){
    float4 v = *(const float4*)(Y + (size_t)row*N_DIM + c4);
    p.x = pack2(v.x, v.y); p.y = pack2(v.z, v.w);
  }
  *(uint2*)(Ybf + (size_t)row*NPAD + c4) = p;
}

// WTbf[k][j] = bf16(W[j][k]) : 2048 x 800 (j in [784,800) -> 0)
__global__ void transpose_w(const float* __restrict__ W, unsigned short* __restrict__ WTbf){
  __shared__ float tile[32][33];
  int k0 = blockIdx.x*32;       // 64 blocks in k
  int j0 = blockIdx.y*32;       // 25 blocks in j (800)
  int tx = threadIdx.x & 31, ty = threadIdx.x >> 5;   // 32 x 8
#pragma unroll
  for (int i=0;i<4;i++){
    int j = j0 + ty + 8*i;
    float v = (j < N_DIM) ? W[(size_t)j*M_DIM + k0 + tx] : 0.0f;
    tile[tx][ty+8*i] = v;
  }
  __syncthreads();
#pragma unroll
  for (int i=0;i<4;i++){
    int k = k0 + ty + 8*i;
    WTbf[(size_t)k*NPAD + j0 + tx] = f2bf(tile[ty+8*i][tx]);
  }
}

// ---------------- Q = W^T W  (fp32 VALU GEMM, one-time, exact-ish) ----------------
// Q[a][b] = sum_j W[j][a] * W[j][b];  grid (16,16), 256 threads, 128x128 tile, BK=16.
__global__ __launch_bounds__(256)
void compute_q(const float* __restrict__ W, float* __restrict__ Q){
  __shared__ float As2[16][132];
  __shared__ float Bs2[16][132];
  const int t = threadIdx.x;
  const int a0 = blockIdx.x*128, b0 = blockIdx.y*128;
  const int ty = t>>4, tx = t&15;
  float acc[8][8];
#pragma unroll
  for (int i=0;i<8;i++)
#pragma unroll
    for (int j=0;j<8;j++) acc[i][j]=0.0f;

  for (int j0=0; j0<N_DIM; j0+=16){
#pragma unroll
    for (int h=0; h<8; ++h){
      int idx = h*256 + t;
      int r = idx>>7, c = idx&127;
      As2[r][c] = W[(size_t)(j0+r)*M_DIM + a0 + c];
      Bs2[r][c] = W[(size_t)(j0+r)*M_DIM + b0 + c];
    }
    __syncthreads();
#pragma unroll
    for (int kk=0; kk<16; ++kk){
      float a[8], b[8];
#pragma unroll
      for (int i=0;i<8;i++) a[i] = As2[kk][ty*8+i];
#pragma unroll
      for (int j=0;j<8;j++) b[j] = Bs2[kk][tx*8+j];
#pragma unroll
      for (int i=0;i<8;i++)
#pragma unroll
        for (int j=0;j<8;j++) acc[i][j] = fmaf(a[i], b[j], acc[i][j]);
    }
    __syncthreads();
  }
#pragma unroll
  for (int i=0;i<8;i++){
    int a = a0 + ty*8 + i;
#pragma unroll
    for (int j=0;j<8;j++) Q[(size_t)a*M_DIM + b0 + tx*8 + j] = acc[i][j];
  }
}

// ---------------- reductions ----------------
__global__ void sumsq_kernel(const float* __restrict__ v, int n, float* __restrict__ acc){
  __shared__ float red[256];
  int t = threadIdx.x;
  float s = 0.0f;
  for (int i = blockIdx.x*256 + t; i < n; i += gridDim.x*256){ float x = v[i]; s = fmaf(x,x,s); }
  red[t] = s; __syncthreads();
  for (int off=128; off>0; off>>=1){ if (t<off) red[t]+=red[t+off]; __syncthreads(); }
  if (t==0) atomicAdd(acc, red[0]);
}

// ---------------- power method on Q (symmetric): x' = (x/||x||) @ Q ----------------
// grid 512 blocks x 256 threads; wave w of block b computes row j = b*4+w (row-contiguous dot).
__global__ void pm_q(const float* __restrict__ x, const float* __restrict__ Q,
                     float* __restrict__ xout){
  __shared__ float red[256];
  int t = threadIdx.x;
  float s = 0.0f;
  for (int k=t; k<M_DIM; k+=256){ float v = x[k]; s = fmaf(v,v,s); }
  red[t]=s; __syncthreads();
  for (int off=128; off>0; off>>=1){ if (t<off) red[t]+=red[t+off]; __syncthreads(); }
  float inv = 1.0f/sqrtf(red[0]);
  int wave = t>>6, lane = t&63;
  int j = blockIdx.x*4 + wave;
  const float* Qr = Q + (size_t)j*M_DIM;
  float acc = 0.0f;
  for (int k=lane; k<M_DIM; k+=64) acc = fmaf(x[k], Qr[k], acc);
  for (int off=32; off>0; off>>=1) acc += __shfl_down(acc, off);
  if (lane==0) xout[j] = acc * inv;
}

// params: [0]=c, [1]=eta=1/c, [2]=lam/c, [3]=||Y||
__global__ void finish_power(const float* __restrict__ xfin, const float* __restrict__ accs,
                             float* __restrict__ params){
  __shared__ float red[256];
  int t = threadIdx.x;
  float s = 0.0f;
  for (int k=t; k<M_DIM; k+=256){ float v = xfin[k]; s = fmaf(v,v,s); }
  red[t]=s; __syncthreads();
  for (int off=128; off>0; off>>=1){ if (t<off) red[t]+=red[t+off]; __syncthreads(); }
  if (t==0){
    float c = sqrtf(red[0]);
    params[0] = c;
    params[1] = 1.0f/c;
    params[2] = 0.1f/c;
    params[3] = sqrtf(accs[0]);
  }
}

__device__ __forceinline__ float softthr(float v, float th){
  float a = fmaxf(fabsf(v) - th, 0.0f);
  return copysignf(a, v);
}

// ================= MFMA GEMM NT: C[i,j] = sum_k A[i,k]*B[j,k] =================
// Tile 64x128, grid (128,7), 256 threads (4 waves, 2x2). A = Zhi bf16 [8192x2048] async.
// MODE 0: B = Wbf bf16 (async). R = A*B^T - Y -> Rbf (bf16, stride NPAD, pads zeroed),
//         ||R||^2 -> nacc.   Epilogue coalesced via LDS chunks.
// MODE 1: B staged manually from fp32 W (Wbf lives in the X region being written).
//         X = A*B^T (fp32 out).
template<int MODE>
__global__ __launch_bounds__(256)
void mfma_nt(const unsigned short* __restrict__ Abf,
             const unsigned short* __restrict__ Bbf,
             const float* __restrict__ Wf,
             const float* __restrict__ Y,
             unsigned short* __restrict__ Rbf,
             float* __restrict__ X,
             float* __restrict__ nacc){
  __shared__ float4 smem4[1024];                       // 16 KB
  unsigned short* As = (unsigned short*)smem4;          // [64 x 32]  4 KB
  unsigned short* Bs = As + 64*32;                      // [128 x 32] 8 KB
  float* fbuf = (float*)smem4;                          // [64 x 64] fp32 chunk, 16 KB

  const int t    = threadIdx.x;
  const int m0   = blockIdx.x*64, n0 = blockIdx.y*128;
  const int wave = t>>6, lane = t&63;
  const int wm2  = wave>>1, wn2 = wave&1;
  const int quad = lane>>4, l15 = lane&15;
  const int lrow = lane>>2;
  const int lk   = (lane&3)*8;
  const int sr   = t>>1;          // manual B staging row (MODE 1)
  const int skq  = (t&1)*16;

  floatx4 acc[2][4];
#pragma unroll
  for (int i=0;i<2;i++)
#pragma unroll
    for (int j=0;j<4;j++) acc[i][j] = (floatx4)(0.0f);

  for (int k0=0; k0<M_DIM; k0+=32){
    // A: 64x32 tile, one async per thread (wave w -> rows w*16..+16)
    async_ld16(Abf + (size_t)(m0 + wave*16 + lrow)*M_DIM + k0 + lk, &As[wave*512]);
    if (MODE==0){
#pragma unroll
      for (int c=0; c<2; ++c){
        int chunk = wave*2 + c;
        async_ld16(Bbf + (size_t)(n0 + chunk*16 + lrow)*M_DIM + k0 + lk, &Bs[chunk*512]);
      }
    } else {
      int j = n0 + sr;
      uint4 p0 = make_uint4(0,0,0,0), p1 = make_uint4(0,0,0,0);
      if (j < N_DIM){
        const float* bp = Wf + (size_t)j*M_DIM + k0 + skq;
        float4 v0 = *(const float4*)(bp+0);
        float4 v1 = *(const float4*)(bp+4);
        float4 v2 = *(const float4*)(bp+8);
        float4 v3 = *(const float4*)(bp+12);
        p0.x=pack2(v0.x,v0.y); p0.y=pack2(v0.z,v0.w); p0.z=pack2(v1.x,v1.y); p0.w=pack2(v1.z,v1.w);
        p1.x=pack2(v2.x,v2.y); p1.y=pack2(v2.z,v2.w); p1.z=pack2(v3.x,v3.y); p1.w=pack2(v3.z,v3.w);
      }
      *(uint4*)&Bs[sr*32 + skq]     = p0;
      *(uint4*)&Bs[sr*32 + skq + 8] = p1;
    }
    __syncthreads();
    short8 af[2], bfr[4];
#pragma unroll
    for (int ti=0; ti<2; ++ti)
      af[ti] = *(const short8*)&As[(wm2*32 + ti*16 + l15)*32 + quad*8];
#pragma unroll
    for (int tj=0; tj<4; ++tj)
      bfr[tj] = *(const short8*)&Bs[(wn2*64 + tj*16 + l15)*32 + quad*8];
#pragma unroll
    for (int ti=0; ti<2; ++ti)
#pragma unroll
      for (int tj=0; tj<4; ++tj)
        acc[ti][tj] = __builtin_amdgcn_mfma_f32_16x16x32_bf16(af[ti], bfr[tj], acc[ti][tj], 0, 0, 0);
    __syncthreads();
  }

  // ---- coalesced epilogue: 2 chunks of [64 rows x 64 cols] through LDS ----
  float ss = 0.0f;
#pragma unroll
  for (int c=0; c<2; ++c){
    if (wn2 == c){
#pragma unroll
      for (int ti=0; ti<2; ++ti)
#pragma unroll
        for (int tj=0; tj<4; ++tj)
#pragma unroll
          for (int r=0; r<4; ++r)
            fbuf[(wm2*32 + ti*16 + quad*4 + r)*64 + tj*16 + l15] = acc[ti][tj][r];
    }
    __syncthreads();
    // read phase: thread t, k=0..3 -> row 16k+(t>>4), cols (t&15)*4 .. +4  (256B/row segments)
#pragma unroll
    for (int k=0; k<4; ++k){
      int row = k*16 + (t>>4);
      int col = (t&15)*4;
      int m = m0 + row;
      int n = n0 + c*64 + col;
      float4 v = *(const float4*)&fbuf[row*64 + col];
      if (MODE==0){
        if (n < N_DIM){
          float4 yv = *(const float4*)(Y + (size_t)m*N_DIM + n);
          float r0 = v.x - yv.x, r1 = v.y - yv.y, r2 = v.z - yv.z, r3 = v.w - yv.w;
          uint2 p; p.x = pack2(r0, r1); p.y = pack2(r2, r3);
          *(uint2*)(Rbf + (size_t)m*NPAD + n) = p;
          ss = fmaf(r0,r0, fmaf(r1,r1, fmaf(r2,r2, fmaf(r3,r3, ss))));
        } else if (n < NPAD){
          *(uint2*)(Rbf + (size_t)m*NPAD + n) = make_uint2(0,0);
        }
      } else {
        if (n < N_DIM) *(float4*)(X + (size_t)m*N_DIM + n) = v;
      }
    }
    __syncthreads();
  }

  if (MODE==0){
    for (int off=32; off>0; off>>=1) ss += __shfl_down(ss, off);
    if (lane==0) atomicAdd(nacc, ss);
  }
}

// ================= MFMA GEMM NN: G[i,n] = sum_j A[i,j]*WT[n,j] ==========
// Tile 128x128, grid (64,16). A = Rbf/Ybf [8192x800] (async), B = WTbf [2048x800] (async).
// State: z as hi/lo bf16 pair; Gamma fp32 (graded output). Coalesced epilogue via LDS chunks.
// MODE 0 (init, A=Ybf): g=soft(eta*G,0.1); Gamma=g; z=g -> hi/lo.
// MODE 1 (iter, A=Rbf): z=hi+lo; g=soft(z-eta*G,lam/c); zn=g+mu*(g-go); store hi/lo.
// MODE 2 (last iter):   g=soft(z-eta*G,lam/c); Gamma=g; Zhi=bf16(g) [A for final X GEMM].
template<int MODE>
__global__ __launch_bounds__(256)
void mfma_nn(const unsigned short* __restrict__ Abf,
             const unsigned short* __restrict__ WTbf,
             float* __restrict__ Gamma,
             unsigned short* __restrict__ Zhi,
             unsigned short* __restrict__ Zlo,
             const float* __restrict__ params,
             float mu){
  __shared__ float4 smem4[1024];                       // 16 KB
  unsigned short* As = (unsigned short*)smem4;          // [128 x 32] 8 KB
  unsigned short* Bs = As + 128*32;                     // [128 x 32] 8 KB
  float* fbuf = (float*)smem4;                          // [128 x 32] fp32 chunk, 16 KB

  const int t    = threadIdx.x;
  const int m0   = blockIdx.x*128, n0 = blockIdx.y*128;
  const int wave = t>>6, lane = t&63;
  const int wm   = wave>>1, wn = wave&1;
  const int quad = lane>>4, l15 = lane&15;
  const int ch0  = wave*2;
  const int lrow = lane>>2;
  const int lk   = (lane&3)*8;

  floatx4 acc[4][4];
#pragma unroll
  for (int i=0;i<4;i++)
#pragma unroll
    for (int j=0;j<4;j++) acc[i][j] = (floatx4)(0.0f);

  for (int k0=0; k0<NPAD; k0+=32){
#pragma unroll
    for (int c=0; c<2; ++c){
      int chunk = ch0 + c;
      async_ld16(Abf  + (size_t)(m0 + chunk*16 + lrow)*NPAD + k0 + lk, &As[chunk*512]);
      async_ld16(WTbf + (size_t)(n0 + chunk*16 + lrow)*NPAD + k0 + lk, &Bs[chunk*512]);
    }
    __syncthreads();
    short8 af[4], bfr[4];
#pragma unroll
    for (int ti=0; ti<4; ++ti)
      af[ti] = *(const short8*)&As[(wm*64 + ti*16 + l15)*32 + quad*8];
#pragma unroll
    for (int tj=0; tj<4; ++tj)
      bfr[tj] = *(const short8*)&Bs[(wn*64 + tj*16 + l15)*32 + quad*8];
#pragma unroll
    for (int ti=0; ti<4; ++ti)
#pragma unroll
      for (int tj=0; tj<4; ++tj)
        acc[ti][tj] = __builtin_amdgcn_mfma_f32_16x16x32_bf16(af[ti], bfr[tj], acc[ti][tj], 0, 0, 0);
    __syncthreads();
  }

  const float eta  = params[1];
  const float lamc = params[2];

  // ---- coalesced epilogue: 4 chunks of [128 rows x 32 cols] through LDS ----
#pragma unroll
  for (int c=0; c<4; ++c){
    if (wn == (c>>1)){
      int tjb = (c&1)*2;
#pragma unroll
      for (int ti=0; ti<4; ++ti)
#pragma unroll
        for (int u=0; u<2; ++u)
#pragma unroll
          for (int r=0; r<4; ++r)
            fbuf[(wm*64 + ti*16 + quad*4 + r)*32 + u*16 + l15] = acc[ti][tjb+u][r];
    }
    __syncthreads();
    // read phase: thread t, k=0..3 -> row 32k+(t>>3), cols (t&7)*4 .. +4  (128B/row segments)
#pragma unroll
    for (int k=0; k<4; ++k){
      int row = k*32 + (t>>3);
      int col = (t&7)*4;
      int m = m0 + row;
      int n = n0 + c*32 + col;
      size_t idx = (size_t)m*M_DIM + n;
      float4 g4 = *(const float4*)&fbuf[row*32 + col];
      float gr[4] = {g4.x, g4.y, g4.z, g4.w};
      float go4[4];
      if (MODE!=0){
        uint2 ph = *(const uint2*)(Zhi + idx);
        uint2 pl = *(const uint2*)(Zlo + idx);
        unsigned short h[4] = {(unsigned short)(ph.x&0xffff),(unsigned short)(ph.x>>16),
                               (unsigned short)(ph.y&0xffff),(unsigned short)(ph.y>>16)};
        unsigned short l[4] = {(unsigned short)(pl.x&0xffff),(unsigned short)(pl.x>>16),
                               (unsigned short)(pl.y&0xffff),(unsigned short)(pl.y>>16)};
        float4 gov = *(const float4*)(Gamma + idx);
        go4[0]=gov.x; go4[1]=gov.y; go4[2]=gov.z; go4[3]=gov.w;
#pragma unroll
        for (int e=0;e<4;e++){
          float zv = bf2f(h[e]) + bf2f(l[e]);
          gr[e] = softthr(zv - eta*gr[e], lamc);
        }
      } else {
#pragma unroll
        for (int e=0;e<4;e++) gr[e] = softthr(eta*gr[e], 0.1f);
      }
      // write Gamma fp32 (coalesced float4)
      *(float4*)(Gamma + idx) = make_float4(gr[0],gr[1],gr[2],gr[3]);
      // write z state
      if (MODE==1){
        float zn[4];
#pragma unroll
        for (int e=0;e<4;e++) zn[e] = gr[e] + mu*(gr[e] - go4[e]);
        unsigned short h0=f2bf(zn[0]), h1=f2bf(zn[1]), h2=f2bf(zn[2]), h3=f2bf(zn[3]);
        uint2 ph; ph.x = (unsigned)h0 | ((unsigned)h1<<16); ph.y = (unsigned)h2 | ((unsigned)h3<<16);
        uint2 pl; pl.x = pack2(zn[0]-bf2f(h0), zn[1]-bf2f(h1));
                  pl.y = pack2(zn[2]-bf2f(h2), zn[3]-bf2f(h3));
        *(uint2*)(Zhi + idx) = ph;
        *(uint2*)(Zlo + idx) = pl;
      } else if (MODE==0){
        unsigned short h0=f2bf(gr[0]), h1=f2bf(gr[1]), h2=f2bf(gr[2]), h3=f2bf(gr[3]);
        uint2 ph; ph.x = (unsigned)h0 | ((unsigned)h1<<16); ph.y = (unsigned)h2 | ((unsigned)h3<<16);
        uint2 pl; pl.x = pack2(gr[0]-bf2f(h0), gr[1]-bf2f(h1));
                  pl.y = pack2(gr[2]-bf2f(h2), gr[3]-bf2f(h3));
        *(uint2*)(Zhi + idx) = ph;
        *(uint2*)(Zlo + idx) = pl;
      } else { // MODE 2: Zhi = bf16(g) for the final X GEMM
        uint2 ph; ph.x = pack2(gr[0], gr[1]); ph.y = pack2(gr[2], gr[3]);
        *(uint2*)(Zhi + idx) = ph;
      }
    }
    __syncthreads();
  }
}

__global__ void norms_finalize(const float* __restrict__ nacc, const float* __restrict__ params,
                               float* __restrict__ out){
  int i = threadIdx.x;
  if (i < NITER) out[i] = sqrtf(nacc[i]) / params[3];
}

extern "C" void kernel_launch(void* const* d_in, const int* in_sizes, int n_in,
                              void* d_out, int out_size, void* d_ws, size_t ws_size,
                              hipStream_t stream){
  const float* Y  = (const float*)d_in[0];
  const float* W  = (const float*)d_in[1];
  float* out      = (float*)d_out;
  float* X        = out;                 // [8192x784] fp32 (written last)
  float* Gamma    = out + XSZ;           // [8192x2048] fp32
  float* norms    = out + XSZ + GSZ;     // [50]

  // ---- ws: exactly 64 MiB (proven budget): z state as hi/lo bf16 pair ----
  unsigned short* Zhi = (unsigned short*)d_ws;           // [8192 x 2048]  33.5 MB
  unsigned short* Zlo = Zhi + (size_t)B_DIM*M_DIM;       // [8192 x 2048]  33.5 MB

  // ---- X-region scratch (dead before final X write), ~23.8 MB of 25.7 MB ----
  // layout: [Wbf][WTbf][Rbf-or-Q][small fp32 scratch]
  unsigned short* Wbf  = (unsigned short*)out;               // [896 x 2048]   3.7 MB
  unsigned short* WTbf = Wbf + (size_t)NROWS_W*M_DIM;        // [2048 x 800]   3.3 MB
  unsigned short* Rbf  = WTbf + (size_t)M_DIM*NPAD;          // [8192 x 800]  13.1 MB (Ybf at init)
  float* Q      = (float*)Rbf;                                // [2048x2048] fp32 16.8 MB (pre-FISTA only)
  float* fsc    = (float*)(Rbf + (size_t)M_DIM*M_DIM*2);      // after max(Rbf,Q) footprint
  float* xb0    = fsc;
  float* xb1    = xb0 + M_DIM;
  float* params = xb1 + M_DIM;
  float* accs   = params + 8;            // accs[0]=||Y||^2, accs[1..50]=per-iter ||R||^2

  setup_kernel<<<dim3(1), dim3(1024), 0, stream>>>(xb0, accs);
  sumsq_kernel<<<dim3(512), dim3(256), 0, stream>>>(Y, XSZ, accs);
  conv_w      <<<dim3(1792), dim3(256), 0, stream>>>(W, Wbf);
  transpose_w <<<dim3(64,25), dim3(256), 0, stream>>>(W, WTbf);

  // power method on Q = W^T W (Q occupies the Rbf slot until finish_power)
  compute_q<<<dim3(16,16), dim3(256), 0, stream>>>(W, Q);
  float* xa = xb0; float* xc = xb1;
  for (int it=0; it<PITER; ++it){
    pm_q<<<dim3(512), dim3(256), 0, stream>>>(xa, Q, xc);
    float* tmp = xa; xa = xc; xc = tmp;
  }
  finish_power<<<dim3(1), dim3(256), 0, stream>>>(xa, accs, params);

  // now Q is dead: convert Y into the Rbf slot for the init GEMM
  conv_y<<<dim3(B_DIM), dim3(256), 0, stream>>>(Y, Rbf);

  // Gamma0 = soft(eta*(Y@W), 0.1); z0 = Gamma0 -> hi/lo
  mfma_nn<0><<<dim3(64,16), dim3(256), 0, stream>>>(Rbf, WTbf, Gamma, Zhi, Zlo, params, 0.0f);

  float tcur = 1.0f;
  for (int it=0; it<NITER; ++it){
    mfma_nt<0><<<dim3(128,7), dim3(256), 0, stream>>>(Zhi, Wbf, nullptr, Y, Rbf, nullptr, accs + 1 + it);
    float tsq = tcur*tcur;
    float tn  = (1.0f + sqrtf(1.0f + 4.0f*tsq)) / 2.0f;
    float mu  = (tcur - 1.0f) / tn;
    tcur = tn;
    if (it < NITER-1)
      mfma_nn<1><<<dim3(64,16), dim3(256), 0, stream>>>(Rbf, WTbf, Gamma, Zhi, Zlo, params, mu);
    else
      mfma_nn<2><<<dim3(64,16), dim3(256), 0, stream>>>(Rbf, WTbf, Gamma, Zhi, Zlo, params, mu);
  }

  // norms BEFORE the final X GEMM (X write covers the scratch tail holding accs/params)
  norms_finalize<<<dim3(1), dim3(64), 0, stream>>>(accs + 1, params, norms);

  // X = Gamma @ W^T  (Zhi holds bf16 Gamma; B staged from fp32 W — Wbf is in the X region)
  mfma_nt<1><<<dim3(128,7), dim3(256), 0, stream>>>(Zhi, nullptr, W, nullptr, nullptr, X, nullptr);
}

// Round 7
// 9277.580 us; speedup vs baseline: 4.6036x; 1.0385x over previous
//
#include <hip/hip_runtime.h>
#include <math.h>

#define B_DIM   8192
#define N_DIM   784
#define NPAD    800          // 25*32, K/N pad for NN GEMM / Rbf
#define NROWS_W 1024         // 4*256, row-pad for Wbf (NT B operand, 256-wide n-tiles)
#define M_DIM   2048
#define XSZ     (B_DIM*N_DIM)
#define GSZ     (B_DIM*M_DIM)
#define NITER   50
#define PITER   100

typedef __attribute__((ext_vector_type(8))) short short8;
typedef __attribute__((ext_vector_type(4))) float floatx4;

// ---------------- async global->LDS (16B per lane, wave-uniform LDS base) ----------------
__device__ __forceinline__ void async_ld16(const unsigned short* g, unsigned short* l){
  __builtin_amdgcn_global_load_lds(
      (const __attribute__((address_space(1))) unsigned int*)g,
      (__attribute__((address_space(3))) unsigned int*)l,
      16, 0, 0);
}

// ---------------- threefry + erfinv (reproduce jax.random.normal(key(1),(1,2048))) ------------
__device__ __forceinline__ unsigned rotl32(unsigned x, int d){ return (x<<d)|(x>>(32-d)); }

__device__ void threefry2x32(unsigned& v0, unsigned& v1){
  const unsigned ks0=0u, ks1=1u, ks2=0x1BD11BDBu;
  unsigned x0=v0+ks0, x1=v1+ks1;
#define RND(R) { x0+=x1; x1=rotl32(x1,R); x1^=x0; }
  RND(13) RND(15) RND(26) RND(6)
  x0+=ks1; x1+=ks2+1u;
  RND(17) RND(29) RND(16) RND(24)
  x0+=ks2; x1+=ks0+2u;
  RND(13) RND(15) RND(26) RND(6)
  x0+=ks0; x1+=ks1+3u;
  RND(17) RND(29) RND(16) RND(24)
  x0+=ks1; x1+=ks2+4u;
  RND(13) RND(15) RND(26) RND(6)
  x0+=ks2; x1+=ks0+5u;
#undef RND
  v0=x0; v1=x1;
}

__device__ float erfinv_f(float x){
  float w = -logf((1.0f-x)*(1.0f+x));
  float p;
  if (w < 5.0f){
    w -= 2.5f;
    p = 2.81022636e-08f;
    p = fmaf(p,w, 3.43273939e-07f);
    p = fmaf(p,w,-3.5233877e-06f);
    p = fmaf(p,w,-4.39150654e-06f);
    p = fmaf(p,w, 0.00021858087f);
    p = fmaf(p,w,-0.00125372503f);
    p = fmaf(p,w,-0.00417768164f);
    p = fmaf(p,w, 0.246640727f);
    p = fmaf(p,w, 1.50140941f);
  } else {
    w = sqrtf(w) - 3.0f;
    p = -0.000200214257f;
    p = fmaf(p,w, 0.000100950558f);
    p = fmaf(p,w, 0.00134934322f);
    p = fmaf(p,w,-0.00367342844f);
    p = fmaf(p,w, 0.00573950773f);
    p = fmaf(p,w,-0.0076224613f);
    p = fmaf(p,w, 0.00943887047f);
    p = fmaf(p,w, 1.00167406f);
    p = fmaf(p,w, 2.83297682f);
  }
  return p*x;
}

__device__ float bits_to_normal(unsigned b){
  unsigned fb = (b>>9) | 0x3f800000u;
  float u01 = __uint_as_float(fb) - 1.0f;
  const float lo = -0.99999994f;
  float u = u01*(1.0f - lo) + lo;
  u = fmaxf(lo, u);
  return 1.41421356237f * erfinv_f(u);
}

__global__ void setup_kernel(float* __restrict__ xbuf0, float* __restrict__ accs){
  int i = threadIdx.x;   // 1024 threads
  if (i < 64) accs[i] = 0.0f;
  unsigned v0 = (unsigned)i, v1 = (unsigned)(1024+i);
  threefry2x32(v0, v1);
  xbuf0[i]        = bits_to_normal(v0);
  xbuf0[1024 + i] = bits_to_normal(v1);
}

// ---------------- bf16 convert helpers ----------------
__device__ __forceinline__ unsigned short f2bf(float f){
  unsigned u = __float_as_uint(f);
  unsigned r = (u + 0x7fffu + ((u>>16)&1u)) >> 16;
  return (unsigned short)r;
}
__device__ __forceinline__ unsigned pack2(float a, float b){
  return (unsigned)f2bf(a) | ((unsigned)f2bf(b) << 16);
}
__device__ __forceinline__ float bf2f(unsigned short s){
  return __uint_as_float(((unsigned)s) << 16);
}

// Wbf[j][k] = bf16(W[j][k]) : 1024 x 2048, rows >=784 zeroed
__global__ void conv_w(const float* __restrict__ W, unsigned short* __restrict__ Wbf){
  int i4 = (blockIdx.x*256 + threadIdx.x)*4;   // over 1024*2048 -> 2048 blocks
  int row = i4 >> 11;
  uint2 p = make_uint2(0,0);
  if (row < N_DIM){
    float4 v = *(const float4*)(W + (size_t)row*M_DIM + (i4 & 2047));
    p.x = pack2(v.x, v.y); p.y = pack2(v.z, v.w);
  }
  *(uint2*)(Wbf + i4) = p;
}

// Ybf[i][j] = bf16(Y[i][j]) : 8192 x 800, cols >=784 zeroed  (stored into Rbf buffer)
__global__ void conv_y(const float* __restrict__ Y, unsigned short* __restrict__ Ybf){
  int row = blockIdx.x;
  int c4 = threadIdx.x*4;
  if (c4 >= NPAD) return;
  uint2 p = make_uint2(0,0);
  if (c4 < N_DIM){
    float4 v = *(const float4*)(Y + (size_t)row*N_DIM + c4);
    p.x = pack2(v.x, v.y); p.y = pack2(v.z, v.w);
  }
  *(uint2*)(Ybf + (size_t)row*NPAD + c4) = p;
}

// WTbf[k][j] = bf16(W[j][k]) : 2048 x 800 (j in [784,800) -> 0)
__global__ void transpose_w(const float* __restrict__ W, unsigned short* __restrict__ WTbf){
  __shared__ float tile[32][33];
  int k0 = blockIdx.x*32;
  int j0 = blockIdx.y*32;
  int tx = threadIdx.x & 31, ty = threadIdx.x >> 5;
#pragma unroll
  for (int i=0;i<4;i++){
    int j = j0 + ty + 8*i;
    float v = (j < N_DIM) ? W[(size_t)j*M_DIM + k0 + tx] : 0.0f;
    tile[tx][ty+8*i] = v;
  }
  __syncthreads();
#pragma unroll
  for (int i=0;i<4;i++){
    int k = k0 + ty + 8*i;
    WTbf[(size_t)k*NPAD + j0 + tx] = f2bf(tile[ty+8*i][tx]);
  }
}

// ---------------- Q = W^T W (fp32 VALU GEMM, one-time, power-method only) ----------------
__global__ __launch_bounds__(256)
void compute_q(const float* __restrict__ W, float* __restrict__ Q){
  __shared__ float As2[16][132];
  __shared__ float Bs2[16][132];
  const int t = threadIdx.x;
  const int a0 = blockIdx.x*128, b0 = blockIdx.y*128;
  const int ty = t>>4, tx = t&15;
  float acc[8][8];
#pragma unroll
  for (int i=0;i<8;i++)
#pragma unroll
    for (int j=0;j<8;j++) acc[i][j]=0.0f;

  for (int j0=0; j0<N_DIM; j0+=16){
#pragma unroll
    for (int h=0; h<8; ++h){
      int idx = h*256 + t;
      int r = idx>>7, c = idx&127;
      As2[r][c] = W[(size_t)(j0+r)*M_DIM + a0 + c];
      Bs2[r][c] = W[(size_t)(j0+r)*M_DIM + b0 + c];
    }
    __syncthreads();
#pragma unroll
    for (int kk=0; kk<16; ++kk){
      float a[8], b[8];
#pragma unroll
      for (int i=0;i<8;i++) a[i] = As2[kk][ty*8+i];
#pragma unroll
      for (int j=0;j<8;j++) b[j] = Bs2[kk][tx*8+j];
#pragma unroll
      for (int i=0;i<8;i++)
#pragma unroll
        for (int j=0;j<8;j++) acc[i][j] = fmaf(a[i], b[j], acc[i][j]);
    }
    __syncthreads();
  }
#pragma unroll
  for (int i=0;i<8;i++){
    int a = a0 + ty*8 + i;
#pragma unroll
    for (int j=0;j<8;j++) Q[(size_t)a*M_DIM + b0 + tx*8 + j] = acc[i][j];
  }
}

// ---------------- reductions ----------------
__global__ void sumsq_kernel(const float* __restrict__ v, int n, float* __restrict__ acc){
  __shared__ float red[256];
  int t = threadIdx.x;
  float s = 0.0f;
  for (int i = blockIdx.x*256 + t; i < n; i += gridDim.x*256){ float x = v[i]; s = fmaf(x,x,s); }
  red[t] = s; __syncthreads();
  for (int off=128; off>0; off>>=1){ if (t<off) red[t]+=red[t+off]; __syncthreads(); }
  if (t==0) atomicAdd(acc, red[0]);
}

// ---------------- power method on Q (symmetric) ----------------
__global__ void pm_q(const float* __restrict__ x, const float* __restrict__ Q,
                     float* __restrict__ xout){
  __shared__ float red[256];
  int t = threadIdx.x;
  float s = 0.0f;
  for (int k=t; k<M_DIM; k+=256){ float v = x[k]; s = fmaf(v,v,s); }
  red[t]=s; __syncthreads();
  for (int off=128; off>0; off>>=1){ if (t<off) red[t]+=red[t+off]; __syncthreads(); }
  float inv = 1.0f/sqrtf(red[0]);
  int wave = t>>6, lane = t&63;
  int j = blockIdx.x*4 + wave;
  const float* Qr = Q + (size_t)j*M_DIM;
  float acc = 0.0f;
  for (int k=lane; k<M_DIM; k+=64) acc = fmaf(x[k], Qr[k], acc);
  for (int off=32; off>0; off>>=1) acc += __shfl_down(acc, off);
  if (lane==0) xout[j] = acc * inv;
}

// params: [0]=c, [1]=eta=1/c, [2]=lam/c, [3]=||Y||
__global__ void finish_power(const float* __restrict__ xfin, const float* __restrict__ accs,
                             float* __restrict__ params){
  __shared__ float red[256];
  int t = threadIdx.x;
  float s = 0.0f;
  for (int k=t; k<M_DIM; k+=256){ float v = xfin[k]; s = fmaf(v,v,s); }
  red[t]=s; __syncthreads();
  for (int off=128; off>0; off>>=1){ if (t<off) red[t]+=red[t+off]; __syncthreads(); }
  if (t==0){
    float c = sqrtf(red[0]);
    params[0] = c;
    params[1] = 1.0f/c;
    params[2] = 0.1f/c;
    params[3] = sqrtf(accs[0]);
  }
}

__device__ __forceinline__ float softthr(float v, float th){
  float a = fmaxf(fabsf(v) - th, 0.0f);
  return copysignf(a, v);
}

// ================= MFMA GEMM NT: C[i,j] = sum_k A[i,k]*B[j,k] =================
// Tile 64x256. Grid 512 (1D, XCD-swizzled: XCD g8 owns a 16m x 4n panel).
// A = Zhi bf16 [8192 x 2048], B = Wbf bf16 [1024 x 2048] (rows>=784 zero), both async.
// MODE 0: R = A*B^T - Y -> Rbf (bf16, stride NPAD, cols [784,800) zeroed), ||R||^2 -> nacc.
// MODE 1: X = A*B^T (fp32 out; A holds bf16 of final Gamma).
template<int MODE>
__global__ __launch_bounds__(256)
void mfma_nt(const unsigned short* __restrict__ Abf,
             const unsigned short* __restrict__ Bbf,
             const float* __restrict__ Y,
             unsigned short* __restrict__ Rbf,
             float* __restrict__ X,
             float* __restrict__ nacc){
  __shared__ float4 smem4[1280];                 // 20 KB: As 4KB + Bs 16KB
  unsigned short* As = (unsigned short*)smem4;   // [64 x 32]
  unsigned short* Bs = As + 64*32;               // [256 x 32]
  float* fbuf = (float*)smem4;                   // [64 x 64] fp32 epilogue chunk (16 KB)

  const int bid = blockIdx.x;
  const int g8  = bid & 7, w = bid >> 3;         // XCD panel: 16m x 4n
  const int m0  = (g8*16 + (w>>2))*64;
  const int n0  = (w & 3)*256;

  const int t    = threadIdx.x;
  const int wave = t>>6, lane = t&63;
  const int wm2  = wave>>1, wn2 = wave&1;        // 2x2 waves over 64x256
  const int quad = lane>>4, l15 = lane&15;
  const int lrow = lane>>2;
  const int lk   = (lane&3)*8;

  floatx4 acc[2][8];
#pragma unroll
  for (int i=0;i<2;i++)
#pragma unroll
    for (int j=0;j<8;j++) acc[i][j] = (floatx4)(0.0f);

  for (int k0=0; k0<M_DIM; k0+=32){
    // A: 64x32 = 4 chunks of 16 rows; one async per thread
    async_ld16(Abf + (size_t)(m0 + wave*16 + lrow)*M_DIM + k0 + lk, &As[wave*512]);
    // B: 256x32 = 16 chunks; 4 per wave
#pragma unroll
    for (int c=0; c<4; ++c){
      int chunk = wave*4 + c;
      async_ld16(Bbf + (size_t)(n0 + chunk*16 + lrow)*M_DIM + k0 + lk, &Bs[chunk*512]);
    }
    __syncthreads();
    short8 af[2], bfr[8];
#pragma unroll
    for (int ti=0; ti<2; ++ti)
      af[ti] = *(const short8*)&As[(wm2*32 + ti*16 + l15)*32 + quad*8];
#pragma unroll
    for (int tj=0; tj<8; ++tj)
      bfr[tj] = *(const short8*)&Bs[(wn2*128 + tj*16 + l15)*32 + quad*8];
#pragma unroll
    for (int ti=0; ti<2; ++ti)
#pragma unroll
      for (int tj=0; tj<8; ++tj)
        acc[ti][tj] = __builtin_amdgcn_mfma_f32_16x16x32_bf16(af[ti], bfr[tj], acc[ti][tj], 0, 0, 0);
    __syncthreads();
  }

  // ---- coalesced epilogue: 4 chunks of [64 rows x 64 cols] via LDS ----
  float ss = 0.0f;
#pragma unroll
  for (int c=0; c<4; ++c){
    if (wn2 == (c>>1)){
      int tb = (c&1)*4;
#pragma unroll
      for (int ti=0; ti<2; ++ti)
#pragma unroll
        for (int u=0; u<4; ++u)
#pragma unroll
          for (int r=0; r<4; ++r)
            fbuf[(wm2*32 + ti*16 + quad*4 + r)*64 + u*16 + l15] = acc[ti][tb+u][r];
    }
    __syncthreads();
#pragma unroll
    for (int k=0; k<4; ++k){
      int row = k*16 + (t>>4);
      int col = (t&15)*4;
      int m = m0 + row;
      int n = n0 + c*64 + col;
      float4 v = *(const float4*)&fbuf[row*64 + col];
      if (MODE==0){
        if (n < N_DIM){
          float4 yv = *(const float4*)(Y + (size_t)m*N_DIM + n);
          float r0 = v.x - yv.x, r1 = v.y - yv.y, r2 = v.z - yv.z, r3 = v.w - yv.w;
          uint2 p; p.x = pack2(r0, r1); p.y = pack2(r2, r3);
          *(uint2*)(Rbf + (size_t)m*NPAD + n) = p;
          ss = fmaf(r0,r0, fmaf(r1,r1, fmaf(r2,r2, fmaf(r3,r3, ss))));
        } else if (n < NPAD){
          *(uint2*)(Rbf + (size_t)m*NPAD + n) = make_uint2(0,0);
        }
      } else {
        if (n < N_DIM) *(float4*)(X + (size_t)m*N_DIM + n) = v;
      }
    }
    __syncthreads();
  }

  if (MODE==0){
    for (int off=32; off>0; off>>=1) ss += __shfl_down(ss, off);
    if (lane==0) atomicAdd(nacc, ss);
  }
}

// ================= MFMA GEMM NN: G[i,n] = sum_j A[i,j]*WT[n,j] ==========
// Tile 128x256. Grid 512 (1D, XCD-swizzled: XCD g8 owns an 8m x 8n panel -> its 1024-row
// A-slab (1.6 MB) + all of WTbf (3.3 MB) are XCD-L2-resident).
// A = Rbf/Ybf [8192 x 800] (async), B = WTbf [2048 x 800] (async).
// State: z as hi/lo bf16 pair; Gamma fp32 (graded output).
// MODE 0 (init, A=Ybf): g=soft(eta*G,0.1); Gamma=g; z=g -> hi/lo.
// MODE 1 (iter, A=Rbf): z=hi+lo; g=soft(z-eta*G,lam/c); zn=g+mu*(g-go); store hi/lo.
// MODE 2 (last iter):   g=soft(z-eta*G,lam/c); Gamma=g; Zhi=bf16(g) [A for final X GEMM].
template<int MODE>
__global__ __launch_bounds__(256)
void mfma_nn(const unsigned short* __restrict__ Abf,
             const unsigned short* __restrict__ WTbf,
             float* __restrict__ Gamma,
             unsigned short* __restrict__ Zhi,
             unsigned short* __restrict__ Zlo,
             const float* __restrict__ params,
             float mu){
  __shared__ float4 smem4[1536];                 // 24 KB: As 8KB + Bs 16KB
  unsigned short* As = (unsigned short*)smem4;   // [128 x 32]
  unsigned short* Bs = As + 128*32;              // [256 x 32]
  float* fbuf = (float*)smem4;                   // [128 x 32] fp32 epilogue chunk (16 KB)

  const int bid = blockIdx.x;
  const int g8  = bid & 7, w = bid >> 3;         // XCD panel: 8m x 8n
  const int m0  = (g8*8 + (w>>3))*128;
  const int n0  = (w & 7)*256;

  const int t    = threadIdx.x;
  const int wave = t>>6, lane = t&63;
  const int wm   = wave>>1, wn = wave&1;         // 2x2 waves over 128x256
  const int quad = lane>>4, l15 = lane&15;
  const int lrow = lane>>2;
  const int lk   = (lane&3)*8;

  floatx4 acc[4][8];
#pragma unroll
  for (int i=0;i<4;i++)
#pragma unroll
    for (int j=0;j<8;j++) acc[i][j] = (floatx4)(0.0f);

  for (int k0=0; k0<NPAD; k0+=32){
    // A: 128x32 = 8 chunks; 2 per wave
#pragma unroll
    for (int c=0; c<2; ++c){
      int chunk = wave*2 + c;
      async_ld16(Abf + (size_t)(m0 + chunk*16 + lrow)*NPAD + k0 + lk, &As[chunk*512]);
    }
    // B: 256x32 = 16 chunks; 4 per wave
#pragma unroll
    for (int c=0; c<4; ++c){
      int chunk = wave*4 + c;
      async_ld16(WTbf + (size_t)(n0 + chunk*16 + lrow)*NPAD + k0 + lk, &Bs[chunk*512]);
    }
    __syncthreads();
    short8 af[4], bfr[8];
#pragma unroll
    for (int ti=0; ti<4; ++ti)
      af[ti] = *(const short8*)&As[(wm*64 + ti*16 + l15)*32 + quad*8];
#pragma unroll
    for (int tj=0; tj<8; ++tj)
      bfr[tj] = *(const short8*)&Bs[(wn*128 + tj*16 + l15)*32 + quad*8];
#pragma unroll
    for (int ti=0; ti<4; ++ti)
#pragma unroll
      for (int tj=0; tj<8; ++tj)
        acc[ti][tj] = __builtin_amdgcn_mfma_f32_16x16x32_bf16(af[ti], bfr[tj], acc[ti][tj], 0, 0, 0);
    __syncthreads();
  }

  const float eta  = params[1];
  const float lamc = params[2];

  // ---- coalesced epilogue: 8 chunks of [128 rows x 32 cols] via LDS ----
#pragma unroll
  for (int c=0; c<8; ++c){
    if (wn == (c>>2)){
      int tb = (c&3)*2;
#pragma unroll
      for (int ti=0; ti<4; ++ti)
#pragma unroll
        for (int u=0; u<2; ++u)
#pragma unroll
          for (int r=0; r<4; ++r)
            fbuf[(wm*64 + ti*16 + quad*4 + r)*32 + u*16 + l15] = acc[ti][tb+u][r];
    }
    __syncthreads();
#pragma unroll
    for (int k=0; k<4; ++k){
      int row = k*32 + (t>>3);
      int col = (t&7)*4;
      int m = m0 + row;
      int n = n0 + c*32 + col;
      size_t idx = (size_t)m*M_DIM + n;
      float4 g4 = *(const float4*)&fbuf[row*32 + col];
      float gr[4] = {g4.x, g4.y, g4.z, g4.w};
      float go4[4];
      if (MODE!=0){
        uint2 ph = *(const uint2*)(Zhi + idx);
        uint2 pl = *(const uint2*)(Zlo + idx);
        unsigned short h[4] = {(unsigned short)(ph.x&0xffff),(unsigned short)(ph.x>>16),
                               (unsigned short)(ph.y&0xffff),(unsigned short)(ph.y>>16)};
        unsigned short l[4] = {(unsigned short)(pl.x&0xffff),(unsigned short)(pl.x>>16),
                               (unsigned short)(pl.y&0xffff),(unsigned short)(pl.y>>16)};
        float4 gov = *(const float4*)(Gamma + idx);
        go4[0]=gov.x; go4[1]=gov.y; go4[2]=gov.z; go4[3]=gov.w;
#pragma unroll
        for (int e=0;e<4;e++){
          float zv = bf2f(h[e]) + bf2f(l[e]);
          gr[e] = softthr(zv - eta*gr[e], lamc);
        }
      } else {
#pragma unroll
        for (int e=0;e<4;e++) gr[e] = softthr(eta*gr[e], 0.1f);
      }
      *(float4*)(Gamma + idx) = make_float4(gr[0],gr[1],gr[2],gr[3]);
      if (MODE==1){
        float zn[4];
#pragma unroll
        for (int e=0;e<4;e++) zn[e] = gr[e] + mu*(gr[e] - go4[e]);
        unsigned short h0=f2bf(zn[0]), h1=f2bf(zn[1]), h2=f2bf(zn[2]), h3=f2bf(zn[3]);
        uint2 ph; ph.x = (unsigned)h0 | ((unsigned)h1<<16); ph.y = (unsigned)h2 | ((unsigned)h3<<16);
        uint2 pl; pl.x = pack2(zn[0]-bf2f(h0), zn[1]-bf2f(h1));
                  pl.y = pack2(zn[2]-bf2f(h2), zn[3]-bf2f(h3));
        *(uint2*)(Zhi + idx) = ph;
        *(uint2*)(Zlo + idx) = pl;
      } else if (MODE==0){
        unsigned short h0=f2bf(gr[0]), h1=f2bf(gr[1]), h2=f2bf(gr[2]), h3=f2bf(gr[3]);
        uint2 ph; ph.x = (unsigned)h0 | ((unsigned)h1<<16); ph.y = (unsigned)h2 | ((unsigned)h3<<16);
        uint2 pl; pl.x = pack2(gr[0]-bf2f(h0), gr[1]-bf2f(h1));
                  pl.y = pack2(gr[2]-bf2f(h2), gr[3]-bf2f(h3));
        *(uint2*)(Zhi + idx) = ph;
        *(uint2*)(Zlo + idx) = pl;
      } else {
        uint2 ph; ph.x = pack2(gr[0], gr[1]); ph.y = pack2(gr[2], gr[3]);
        *(uint2*)(Zhi + idx) = ph;
      }
    }
    __syncthreads();
  }
}

__global__ void norms_finalize(const float* __restrict__ nacc, const float* __restrict__ params,
                               float* __restrict__ out){
  int i = threadIdx.x;
  if (i < NITER) out[i] = sqrtf(nacc[i]) / params[3];
}

extern "C" void kernel_launch(void* const* d_in, const int* in_sizes, int n_in,
                              void* d_out, int out_size, void* d_ws, size_t ws_size,
                              hipStream_t stream){
  const float* Y  = (const float*)d_in[0];
  const float* W  = (const float*)d_in[1];
  float* out      = (float*)d_out;
  float* X        = out;
  float* Gamma    = out + XSZ;
  float* norms    = out + XSZ + GSZ;

  // ---- all scratch in ws (~105 MB; ws proven >= 134 MB in round 6) ----
  unsigned short* Zhi  = (unsigned short*)d_ws;            // [8192x2048] 33.55 MB
  unsigned short* Zlo  = Zhi  + (size_t)GSZ;               // [8192x2048] 33.55 MB
  unsigned short* Rbf  = Zlo  + (size_t)GSZ;               // [8192x800]  13.11 MB (Ybf at init)
  unsigned short* Wbf  = Rbf  + (size_t)B_DIM*NPAD;        // [1024x2048]  4.19 MB
  unsigned short* WTbf = Wbf  + (size_t)NROWS_W*M_DIM;     // [2048x800]   3.28 MB
  float* Q      = (float*)(WTbf + (size_t)M_DIM*NPAD);     // [2048x2048] 16.78 MB
  float* xb0    = Q + (size_t)M_DIM*M_DIM;
  float* xb1    = xb0 + M_DIM;
  float* params = xb1 + M_DIM;
  float* accs   = params + 8;    // accs[0]=||Y||^2, accs[1..50]=per-iter ||R||^2

  setup_kernel<<<dim3(1), dim3(1024), 0, stream>>>(xb0, accs);
  sumsq_kernel<<<dim3(512), dim3(256), 0, stream>>>(Y, XSZ, accs);
  conv_w      <<<dim3(2048), dim3(256), 0, stream>>>(W, Wbf);
  transpose_w <<<dim3(64,25), dim3(256), 0, stream>>>(W, WTbf);
  conv_y      <<<dim3(B_DIM), dim3(256), 0, stream>>>(Y, Rbf);   // Rbf := Ybf for init GEMM

  compute_q<<<dim3(16,16), dim3(256), 0, stream>>>(W, Q);
  float* xa = xb0; float* xc = xb1;
  for (int it=0; it<PITER; ++it){
    pm_q<<<dim3(512), dim3(256), 0, stream>>>(xa, Q, xc);
    float* tmp = xa; xa = xc; xc = tmp;
  }
  finish_power<<<dim3(1), dim3(256), 0, stream>>>(xa, accs, params);

  // Gamma0 = soft(eta*(Y@W), 0.1); z0 = Gamma0 -> hi/lo
  mfma_nn<0><<<dim3(512), dim3(256), 0, stream>>>(Rbf, WTbf, Gamma, Zhi, Zlo, params, 0.0f);

  float tcur = 1.0f;
  for (int it=0; it<NITER; ++it){
    mfma_nt<0><<<dim3(512), dim3(256), 0, stream>>>(Zhi, Wbf, Y, Rbf, nullptr, accs + 1 + it);
    float tsq = tcur*tcur;
    float tn  = (1.0f + sqrtf(1.0f + 4.0f*tsq)) / 2.0f;
    float mu  = (tcur - 1.0f) / tn;
    tcur = tn;
    if (it < NITER-1)
      mfma_nn<1><<<dim3(512), dim3(256), 0, stream>>>(Rbf, WTbf, Gamma, Zhi, Zlo, params, mu);
    else
      mfma_nn<2><<<dim3(512), dim3(256), 0, stream>>>(Rbf, WTbf, Gamma, Zhi, Zlo, params, mu);
  }

  norms_finalize<<<dim3(1), dim3(64), 0, stream>>>(accs + 1, params, norms);

  // X = Gamma @ W^T  (Zhi holds bf16 Gamma; Wbf in ws -> no aliasing, async B path)
  mfma_nt<1><<<dim3(512), dim3(256), 0, stream>>>(Zhi, Wbf, nullptr, nullptr, X, nullptr);
}